// Round 4
// baseline (268.070 us; speedup 1.0000x reference)
//
#include <hip/hip_runtime.h>
#include <math.h>

// MultiHeadedAttention  B=2, S=2048, D=1024, H=16, DH=64 (fp32 in/out)
// R14: output projection rebuilt as the qkv M128 double-GLDS structure.
//  - attn epilogue writes interleaved ctx2[4096][2048] bf16 (hi,lo pairs,
//    one 4B store per pair).
//  - wsplit z==3 writes Wo2[1024][2048] with each weight duplicated into
//    (hi,lo) slots -> out = ctx2 @ Wo2^T + bo is ONE bf16 GEMM, K=2048,
//    via sweep128bb<2048> (same kernel shape as qkv, which runs ~780 TF).
//  - sweep64p / ctxHi / ctxLo deleted.
// qkv/acast/attn-core/mask_pack unchanged from R13.
// ws: Qbf@0 Kbf@8M Vt@16M mpk@24M Whi@25M Wo2@31M ctx2@35M Abf@51M (75MB)

constexpr int Bc  = 2;
constexpr int Sc  = 2048;
constexpr int Dc  = 1024;
constexpr int Hc  = 16;
constexpr int DHc = 64;
constexpr int BSc = Bc * Sc;     // 4096

constexpr float LOG2E = 1.4426950408889634f;

typedef __bf16 bf16x8 __attribute__((ext_vector_type(8)));
typedef __bf16 bf16x4 __attribute__((ext_vector_type(4)));
typedef __bf16 bf16x2 __attribute__((ext_vector_type(2)));
typedef float  f32x4  __attribute__((ext_vector_type(4)));
typedef float  f32x16 __attribute__((ext_vector_type(16)));
typedef unsigned uint32x2 __attribute__((ext_vector_type(2)));
typedef unsigned uint32x4 __attribute__((ext_vector_type(4)));

#define GLDS16(gp, lp) __builtin_amdgcn_global_load_lds( \
    (const __attribute__((address_space(1))) void*)(gp), \
    (__attribute__((address_space(3))) void*)(lp), 16, 0, 0)

// ---------------------------------------------------------------------------
// Weight cast: z<3 -> Whi[z] = RNE bf16 of {Wq,Wk,Wv}; z==3 -> Wo2 with each
// weight duplicated into (hi,lo) interleaved slots: Wo2[col][2k]=Wo2[col][2k+1]=Wo[col][k].
// ---------------------------------------------------------------------------
__global__ __launch_bounds__(256)
void wsplit(const float* __restrict__ W0, const float* __restrict__ W1,
            const float* __restrict__ W2, const float* __restrict__ W3,
            __bf16* __restrict__ out, __bf16* __restrict__ out2)
{
    const float* src[4] = {W0, W1, W2, W3};
    const int z = blockIdx.y;
    const size_t idx = ((size_t)blockIdx.x * 256 + threadIdx.x) * 4;
    const float4 v = *(const float4*)&src[z][idx];
    if (z == 3) {
        bf16x8 o;
        o[0] = (__bf16)v.x; o[1] = (__bf16)v.x;
        o[2] = (__bf16)v.y; o[3] = (__bf16)v.y;
        o[4] = (__bf16)v.z; o[5] = (__bf16)v.z;
        o[6] = (__bf16)v.w; o[7] = (__bf16)v.w;
        *(bf16x8*)&out2[idx * 2] = o;
    } else {
        bf16x4 o;
        o[0] = (__bf16)v.x; o[1] = (__bf16)v.y; o[2] = (__bf16)v.z; o[3] = (__bf16)v.w;
        *(bf16x4*)&out[(size_t)z * Dc * Dc + idx] = o;
    }
}

// ---------------------------------------------------------------------------
// Activation cast: Abf[z] = RNE bf16 of {query,key,value}, 8 elems/thread.
// ---------------------------------------------------------------------------
__global__ __launch_bounds__(256)
void acast(const float* __restrict__ A0, const float* __restrict__ A1,
           const float* __restrict__ A2, __bf16* __restrict__ out)
{
    const float* src[3] = {A0, A1, A2};
    const int z = blockIdx.y;
    const size_t idx = ((size_t)blockIdx.x * 256 + threadIdx.x) * 8;
    const float4 a = *(const float4*)&src[z][idx];
    const float4 b = *(const float4*)&src[z][idx + 4];
    bf16x8 o;
    o[0] = (__bf16)a.x; o[1] = (__bf16)a.y; o[2] = (__bf16)a.z; o[3] = (__bf16)a.w;
    o[4] = (__bf16)b.x; o[5] = (__bf16)b.y; o[6] = (__bf16)b.z; o[7] = (__bf16)b.w;
    *(bf16x8*)&out[(size_t)z * BSc * Dc + idx] = o;
}

// ---------------------------------------------------------------------------
// Pure double-GLDS K-sweep, M-tile 128: A and W both bf16, both staged via
// global_load_lds into XOR-swizzled dbuf tiles. One barrier per k-iter.
// KD = K dimension (row stride of both A and W).
// ---------------------------------------------------------------------------
template<int KD>
__device__ __forceinline__ void sweep128bb(const __bf16* __restrict__ A,
                                           const __bf16* __restrict__ Wh,
                                           char* AsB, char* WsB,
                                           int gm0, int gn0, f32x4 acc[4][4])
{
    const int tid  = threadIdx.x;
    const int w    = tid >> 6;
    const int lane = tid & 63;
    const int cc   = lane & 15;
    const int g    = lane >> 4;
    const int wm   = (w & 1) * 64;
    const int wn   = (w >> 1) * 64;

    int wrow[4], wchk[4];
#pragma unroll
    for (int r = 0; r < 4; ++r) {
        const int L = r * 256 + tid;
        wrow[r] = L >> 3;
        wchk[r] = (L & 7) ^ (wrow[r] & 7);
    }

    // ---- prologue: stage tile 0 into buf 0 ----
#pragma unroll
    for (int r = 0; r < 4; ++r) {
        GLDS16(Wh + (size_t)(gn0 + wrow[r]) * KD + wchk[r] * 8,
               WsB + (r * 256 + tid) * 16);
        GLDS16(A + (size_t)(gm0 + wrow[r]) * KD + wchk[r] * 8,
               AsB + (r * 256 + tid) * 16);
    }

    for (int it = 0; it < KD / 64; ++it) {
        const char* As = AsB + (it & 1) * 16384;
        const char* Ws = WsB + (it & 1) * 16384;
        __syncthreads();   // drains tile-it GLDS (issued last iter)

        if (it + 1 < KD / 64) {
            const int kn = (it + 1) * 64;
            char* Wn = WsB + ((it + 1) & 1) * 16384;
            char* An = AsB + ((it + 1) & 1) * 16384;
#pragma unroll
            for (int r = 0; r < 4; ++r) {
                GLDS16(Wh + (size_t)(gn0 + wrow[r]) * KD + kn + wchk[r] * 8,
                       Wn + (r * 256 + tid) * 16);
                GLDS16(A + (size_t)(gm0 + wrow[r]) * KD + kn + wchk[r] * 8,
                       An + (r * 256 + tid) * 16);
            }
        }

        // ---- compute tile it ----
        __builtin_amdgcn_s_setprio(1);
#pragma unroll
        for (int kk = 0; kk < 2; ++kk) {
            const int cb4 = (kk * 4 + g) << 4;
            bf16x8 af[4], bfr[4];
#pragma unroll
            for (int mt = 0; mt < 4; ++mt) {
                const int row = wm + mt * 16 + cc;
                af[mt] = *(const bf16x8*)(As + row * 128 + (cb4 ^ ((row & 7) << 4)));
            }
#pragma unroll
            for (int nt = 0; nt < 4; ++nt) {
                const int row = wn + nt * 16 + cc;
                bfr[nt] = *(const bf16x8*)(Ws + row * 128 + (cb4 ^ ((row & 7) << 4)));
            }
#pragma unroll
            for (int mt = 0; mt < 4; ++mt)
#pragma unroll
                for (int nt = 0; nt < 4; ++nt)
                    acc[mt][nt] = __builtin_amdgcn_mfma_f32_16x16x32_bf16(
                        af[mt], bfr[nt], acc[mt][nt], 0, 0, 0);
        }
        __builtin_amdgcn_s_setprio(0);
    }
}

// ---------------------------------------------------------------------------
// QKV projection (double-GLDS). z==2 writes V^T [BH,DH,S] directly.
// ---------------------------------------------------------------------------
__global__ __launch_bounds__(256)
void qkv_mfma(const __bf16* __restrict__ Abf, const __bf16* __restrict__ Whi,
              const float* __restrict__ bq, const float* __restrict__ bk,
              const float* __restrict__ bv,
              __bf16* __restrict__ Qo, __bf16* __restrict__ Ko, __bf16* __restrict__ Vt)
{
    __shared__ __align__(16) char smem[65536];   // A dbuf 32K | W dbuf 32K

    const int z = blockIdx.z;
    const float* bias = (z == 0) ? bq : (z == 1) ? bk : bv;
    const float scale = (z == 0) ? 0.125f * LOG2E : 1.0f;
    const __bf16* A   = Abf + (size_t)z * BSc * Dc;
    const __bf16* Wh  = Whi + (size_t)z * Dc * Dc;

    const int gm0 = blockIdx.x * 128;
    const int gn0 = blockIdx.y * 128;

    f32x4 acc[4][4];
#pragma unroll
    for (int mt = 0; mt < 4; ++mt)
#pragma unroll
        for (int nt = 0; nt < 4; ++nt) acc[mt][nt] = {0.f, 0.f, 0.f, 0.f};

    sweep128bb<Dc>(A, Wh, smem, smem + 32768, gm0, gn0, acc);

    const int tid = threadIdx.x;
    const int w = tid >> 6, lane = tid & 63;
    const int cc = lane & 15, g = lane >> 4;
    const int wm = (w & 1) * 64, wn = (w >> 1) * 64;

    float bias4[4];
#pragma unroll
    for (int nt = 0; nt < 4; ++nt) bias4[nt] = bias[gn0 + wn + nt * 16 + cc];

    if (z == 2) {
#pragma unroll
        for (int mt = 0; mt < 4; ++mt)
#pragma unroll
            for (int nt = 0; nt < 4; ++nt) {
                const int col = gn0 + wn + nt * 16 + cc;
                const int h = col >> 6, dh = col & 63;
                const int row0 = gm0 + wm + mt * 16 + g * 4;
                const int b = row0 >> 11, s0 = row0 & 2047;
                bf16x4 vv;
#pragma unroll
                for (int reg = 0; reg < 4; ++reg)
                    vv[reg] = (__bf16)(acc[mt][nt][reg] + bias4[nt]);
                *(bf16x4*)&Vt[(((size_t)(b * Hc + h)) * DHc + dh) * Sc + s0] = vv;
            }
    } else {
        __bf16* O = (z == 0) ? Qo : Ko;
#pragma unroll
        for (int mt = 0; mt < 4; ++mt)
#pragma unroll
            for (int nt = 0; nt < 4; ++nt) {
                const int col = gn0 + wn + nt * 16 + cc;
                const int h = col >> 6, dh = col & 63;
#pragma unroll
                for (int reg = 0; reg < 4; ++reg) {
                    const int row = gm0 + wm + mt * 16 + g * 4 + reg;
                    const int b = row >> 11, s = row & 2047;
                    O[(((size_t)(b * Hc + h)) * Sc + s) * DHc + dh] =
                        (__bf16)((acc[mt][nt][reg] + bias4[nt]) * scale);
                }
            }
    }
}

// ---------------------------------------------------------------------------
// Output projection: out = ctx2 @ Wo2^T + bo (K=2048 interleaved hi/lo).
// Same M128 double-GLDS structure as qkv.
// ---------------------------------------------------------------------------
__global__ __launch_bounds__(256)
void out_mfma(const __bf16* __restrict__ ctx2, const __bf16* __restrict__ Wo2,
              const float* __restrict__ bo, float* __restrict__ out)
{
    __shared__ __align__(16) char smem[65536];   // A dbuf 32K | W dbuf 32K

    const int gm0 = blockIdx.x * 128;
    const int gn0 = blockIdx.y * 128;

    f32x4 acc[4][4];
#pragma unroll
    for (int mt = 0; mt < 4; ++mt)
#pragma unroll
        for (int nt = 0; nt < 4; ++nt) acc[mt][nt] = {0.f, 0.f, 0.f, 0.f};

    sweep128bb<2 * Dc>(ctx2, Wo2, smem, smem + 32768, gm0, gn0, acc);

    const int tid = threadIdx.x;
    const int w = tid >> 6, lane = tid & 63;
    const int cc = lane & 15, g = lane >> 4;
    const int wm = (w & 1) * 64, wn = (w >> 1) * 64;

    float bias4[4];
#pragma unroll
    for (int nt = 0; nt < 4; ++nt) bias4[nt] = bo[gn0 + wn + nt * 16 + cc];

#pragma unroll
    for (int mt = 0; mt < 4; ++mt)
#pragma unroll
        for (int nt = 0; nt < 4; ++nt) {
            const int col = gn0 + wn + nt * 16 + cc;
#pragma unroll
            for (int reg = 0; reg < 4; ++reg) {
                const int row = gm0 + wm + mt * 16 + g * 4 + reg;
                out[(size_t)row * Dc + col] = acc[mt][nt][reg] + bias4[nt];
            }
        }
}

// ---------------------------------------------------------------------------
// Bitpack mask: each wave packs 4 u64 words (256 elements).
// ---------------------------------------------------------------------------
__global__ __launch_bounds__(256)
void mask_pack(const int* __restrict__ mask, unsigned long long* __restrict__ out)
{
    const int lane = threadIdx.x & 63;
    const size_t waveBase = ((size_t)blockIdx.x * 4 + (threadIdx.x >> 6)) * 256;
    unsigned long long b0 = __ballot(mask[waveBase + lane]        != 0);
    unsigned long long b1 = __ballot(mask[waveBase + 64 + lane]   != 0);
    unsigned long long b2 = __ballot(mask[waveBase + 128 + lane]  != 0);
    unsigned long long b3 = __ballot(mask[waveBase + 192 + lane]  != 0);
    if (lane == 0) {
        unsigned long long* dst = out + (waveBase >> 6);
        dst[0] = b0; dst[1] = b1; dst[2] = b2; dst[3] = b3;
    }
}

// ---------------------------------------------------------------------------
// Flash attention: 32x32x16 MFMA, swapped QK^T (P[k][q] in-register),
// softmax in-register, P->PV A-frags via cvt-pack + v_permlane32_swap.
// 4 waves x 32 q-rows = 128 q/block, grid 16x32 = 512 blocks. K/V dbuf 32KB.
// Epilogue writes interleaved ctx2 (hi,lo) pairs.
// ---------------------------------------------------------------------------
__global__ __launch_bounds__(256, 2)
void attn_mfma(const __bf16* __restrict__ Q, const __bf16* __restrict__ K,
               const __bf16* __restrict__ Vt,
               const unsigned long long* __restrict__ mp,
               __bf16* __restrict__ ctx2)
{
    __shared__ __align__(16) char smem[32768];   // K/V dbuf: 2 x (8K K | 8K V)

    const int tid  = threadIdx.x;
    const int w    = tid >> 6;
    const int lane = tid & 63;
    const int c    = lane & 31;          // 32x32 col / q-row / k-row index
    const int u    = lane >> 5;          // half-wave
    const int bh   = blockIdx.y;
    const int b    = bh >> 4;
    const int h    = bh & 15;
    const int qw   = blockIdx.x * 128 + w * 32;   // 32 q-rows per wave

    const __bf16* Qb  = Q  + (size_t)bh * Sc * DHc;
    const __bf16* Kb  = K  + (size_t)bh * Sc * DHc;
    const __bf16* Vtb = Vt + (size_t)bh * DHc * Sc;

    // Q fragments (B-operand of swapped QK^T): qa[ch] = Q[qw+c][16ch+8u .. +7]
    bf16x8 qa[4];
#pragma unroll
    for (int ch = 0; ch < 4; ++ch)
        qa[ch] = *(const bf16x8*)&Qb[(size_t)(qw + c) * DHc + ch * 16 + u * 8];

    f32x16 o[2];
#pragma unroll
    for (int dt = 0; dt < 2; ++dt)
#pragma unroll
        for (int i = 0; i < 16; ++i) o[dt][i] = 0.f;
    float lp[4] = {0.f, 0.f, 0.f, 0.f};

    // staging: identity rows, XOR-swizzled 16B granules
    const int ci[2] = {tid, 256 + tid};
    int rowi[2], ski[2];
#pragma unroll
    for (int i = 0; i < 2; ++i) {
        rowi[i] = ci[i] >> 3;
        ski[i]  = (ci[i] & 7) ^ (rowi[i] & 7);
    }

#pragma unroll
    for (int i = 0; i < 2; ++i) {
        GLDS16(Kb + (size_t)rowi[i] * DHc + ski[i] * 8,
               smem + ci[i] * 16);
        GLDS16(Vtb + (size_t)rowi[i] * Sc + ski[i] * 8,
               smem + 8192 + ci[i] * 16);
    }

    for (int it = 0; it < 32; ++it) {
        const char* Ks = smem + (it & 1) * 16384;
        const char* Vs = Ks + 8192;

        __syncthreads();

        if (it + 1 < 32) {
            char* Kn = smem + ((it + 1) & 1) * 16384;
            const int kn = (it + 1) * 64;
#pragma unroll
            for (int i = 0; i < 2; ++i) {
                GLDS16(Kb + (size_t)(kn + rowi[i]) * DHc + ski[i] * 8,
                       Kn + ci[i] * 16);
                GLDS16(Vtb + (size_t)rowi[i] * Sc + kn + ski[i] * 8,
                       Kn + 8192 + ci[i] * 16);
            }
        }

        // one mask word per lane: q = qw + c, 64 k-bits of this tile
        const unsigned long long mw =
            mp[((size_t)(b * Sc + qw + c) << 5) + it];

        // ---- QK^T (swapped): sc[nt] = K[32nt..+31] . Q^T  -> P[k][q=c] ----
        f32x16 sc[2];
        __builtin_amdgcn_s_setprio(1);
#pragma unroll
        for (int nt = 0; nt < 2; ++nt) {
            f32x16 z;
#pragma unroll
            for (int i = 0; i < 16; ++i) z[i] = -24.f;
#pragma unroll
            for (int ch = 0; ch < 4; ++ch) {
                const int row = nt * 32 + c;
                const bf16x8 kb = *(const bf16x8*)
                    (Ks + row * 128 + ((ch * 32 + u * 16) ^ ((row & 7) << 4)));
                z = __builtin_amdgcn_mfma_f32_32x32x16_bf16(kb, qa[ch], z, 0, 0, 0);
            }
            sc[nt] = z;
        }
        __builtin_amdgcn_s_setprio(0);

        // ---- softmax in-register; reg i of tile nt is k = 32nt+8(i>>2)+4u+(i&3)
        unsigned pk[2][4][2];
#pragma unroll
        for (int nt = 0; nt < 2; ++nt)
#pragma unroll
            for (int rr = 0; rr < 4; ++rr) {
                const unsigned nib =
                    (unsigned)(mw >> (nt * 32 + rr * 8 + u * 4)) & 0xFu;
                float pv[4];
#pragma unroll
                for (int r = 0; r < 4; ++r) {
                    float p = __builtin_amdgcn_exp2f(sc[nt][rr * 4 + r]);
                    p = (nib & (1u << r)) ? 0.f : p;
                    lp[rr] += p;
                    pv[r] = p;
                }
                bf16x2 t0; t0[0] = (__bf16)pv[0]; t0[1] = (__bf16)pv[1];
                bf16x2 t1; t1[0] = (__bf16)pv[2]; t1[1] = (__bf16)pv[3];
                pk[nt][rr][0] = __builtin_bit_cast(unsigned, t0);
                pk[nt][rr][1] = __builtin_bit_cast(unsigned, t1);
            }

        // ---- redistribute to PV A-frags: one swap fills two words ----
        bf16x8 pa[4];
#pragma unroll
        for (int kc = 0; kc < 4; ++kc) {
            const int nt = kc >> 1;
            const int r0 = (kc & 1) * 2;
            uint32x2 s0 = __builtin_amdgcn_permlane32_swap(
                pk[nt][r0][0], pk[nt][r0 + 1][0], false, false);
            uint32x2 s1 = __builtin_amdgcn_permlane32_swap(
                pk[nt][r0][1], pk[nt][r0 + 1][1], false, false);
            uint32x4 wds;
            wds[0] = s0[0]; wds[1] = s1[0]; wds[2] = s0[1]; wds[3] = s1[1];
            pa[kc] = __builtin_bit_cast(bf16x8, wds);
        }

        // ---- PV: o[dt] += P . V[., 32dt..+31] ----
        __builtin_amdgcn_s_setprio(1);
#pragma unroll
        for (int dt = 0; dt < 2; ++dt)
#pragma unroll
            for (int kc = 0; kc < 4; ++kc) {
                const int row = dt * 32 + c;
                const bf16x8 vb = *(const bf16x8*)
                    (Vs + row * 128 + ((kc * 32 + u * 16) ^ ((row & 7) << 4)));
                o[dt] = __builtin_amdgcn_mfma_f32_32x32x16_bf16(pa[kc], vb, o[dt], 0, 0, 0);
            }
        __builtin_amdgcn_s_setprio(0);
    }

    // ---- epilogue: row sums live at q=c; redistribute to D-row layout ----
    float lsum = (lp[0] + lp[1]) + (lp[2] + lp[3]);
    lsum += __shfl_xor(lsum, 32);
    const float linv = 1.0f / lsum;

    float inv[16];
#pragma unroll
    for (int i = 0; i < 16; ++i)
        inv[i] = __shfl(linv, (i & 3) + 8 * (i >> 2) + 4 * u);

#pragma unroll
    for (int dt = 0; dt < 2; ++dt)
#pragma unroll
        for (int i = 0; i < 16; ++i) {
            const int q = qw + (i & 3) + 8 * (i >> 2) + 4 * u;
            const int col = h * 64 + dt * 32 + c;
            const float v = o[dt][i] * inv[i];
            const __bf16 hi = (__bf16)v;
            bf16x2 hv;
            hv[0] = hi;
            hv[1] = (__bf16)(v - (float)hi);
            *(bf16x2*)&ctx2[(((size_t)b * Sc + q) * Dc + col) * 2] = hv;
        }
}

extern "C" void kernel_launch(void* const* d_in, const int* in_sizes, int n_in,
                              void* d_out, int out_size, void* d_ws, size_t ws_size,
                              hipStream_t stream)
{
    const float* key   = (const float*)d_in[0];
    const float* value = (const float*)d_in[1];
    const float* query = (const float*)d_in[2];
    const int*   mask  = (const int*)  d_in[3];
    const float* Wq    = (const float*)d_in[4];
    const float* bq    = (const float*)d_in[5];
    const float* Wk    = (const float*)d_in[6];
    const float* bk    = (const float*)d_in[7];
    const float* Wv    = (const float*)d_in[8];
    const float* bv    = (const float*)d_in[9];
    const float* Wo    = (const float*)d_in[10];
    const float* bo    = (const float*)d_in[11];
    float* out = (float*)d_out;

    char* wsb = (char*)d_ws;
    __bf16* Qbf  = (__bf16*)(wsb);                                 // 8 MB
    __bf16* Kbf  = (__bf16*)(wsb + ((size_t)8  << 20));            // 8 MB
    __bf16* Vt   = (__bf16*)(wsb + ((size_t)16 << 20));            // 8 MB
    unsigned long long* mpk = (unsigned long long*)(wsb + ((size_t)24 << 20)); // 1 MB
    __bf16* Whi  = (__bf16*)(wsb + ((size_t)25 << 20));            // 6 MB (Wq,Wk,Wv)
    __bf16* Wo2  = (__bf16*)(wsb + ((size_t)31 << 20));            // 4 MB
    __bf16* ctx2 = (__bf16*)(wsb + ((size_t)35 << 20));            // 16 MB
    __bf16* Abf  = (__bf16*)(wsb + ((size_t)51 << 20));            // 24 MB

    dim3 gws(Dc * Dc / (256 * 4), 4);
    wsplit<<<gws, 256, 0, stream>>>(Wq, Wk, Wv, Wo, Whi, Wo2);

    dim3 gac(BSc * Dc / (256 * 8), 3);
    acast<<<gac, 256, 0, stream>>>(query, key, value, Abf);

    dim3 gqkv(BSc / 128, Dc / 128, 3);
    qkv_mfma<<<gqkv, 256, 0, stream>>>(Abf, Whi, bq, bk, bv, Qbf, Kbf, Vt);

    const int mask_n = Bc * Sc * Sc;
    mask_pack<<<mask_n / 1024, 256, 0, stream>>>(mask, mpk);

    dim3 gattn(Sc / 128, Bc * Hc);
    attn_mfma<<<gattn, 256, 0, stream>>>(Qbf, Kbf, Vt, mpk, ctx2);

    dim3 gout(BSc / 128, Dc / 128);
    out_mfma<<<gout, 256, 0, stream>>>(ctx2, Wo2, bo, out);
}

// Round 5
// 267.409 us; speedup vs baseline: 1.0025x; 1.0025x over previous
//
#include <hip/hip_runtime.h>
#include <math.h>

// MultiHeadedAttention  B=2, S=2048, D=1024, H=16, DH=64 (fp32 in/out)
// R15:
//  - out_mfma regression fix: M64xN128 K=2048 sweep64bb, grid (64,8)=512
//    blocks = 2/CU (R14's M128 had 256 blocks = 1/CU, fully exposed
//    latency). LDS 48KB: W dbuf 32K + A dbuf 16K.
//  - attn: split dependent MFMA accumulation chains. QK^T: z0/z1 (2-deep
//    each, summed per iter). PV: o/o2 (summed once in epilogue). Same fp32
//    math, 2x MFMA ILP per wave.
// qkv/acast/wsplit/mask_pack unchanged from R14.
// ws: Qbf@0 Kbf@8M Vt@16M mpk@24M Whi@25M Wo2@31M ctx2@35M Abf@51M (75MB)

constexpr int Bc  = 2;
constexpr int Sc  = 2048;
constexpr int Dc  = 1024;
constexpr int Hc  = 16;
constexpr int DHc = 64;
constexpr int BSc = Bc * Sc;     // 4096

constexpr float LOG2E = 1.4426950408889634f;

typedef __bf16 bf16x8 __attribute__((ext_vector_type(8)));
typedef __bf16 bf16x4 __attribute__((ext_vector_type(4)));
typedef __bf16 bf16x2 __attribute__((ext_vector_type(2)));
typedef float  f32x4  __attribute__((ext_vector_type(4)));
typedef float  f32x16 __attribute__((ext_vector_type(16)));
typedef unsigned uint32x2 __attribute__((ext_vector_type(2)));
typedef unsigned uint32x4 __attribute__((ext_vector_type(4)));

#define GLDS16(gp, lp) __builtin_amdgcn_global_load_lds( \
    (const __attribute__((address_space(1))) void*)(gp), \
    (__attribute__((address_space(3))) void*)(lp), 16, 0, 0)

// ---------------------------------------------------------------------------
// Weight cast: z<3 -> Whi[z] = RNE bf16 of {Wq,Wk,Wv}; z==3 -> Wo2 with each
// weight duplicated into (hi,lo) interleaved slots.
// ---------------------------------------------------------------------------
__global__ __launch_bounds__(256)
void wsplit(const float* __restrict__ W0, const float* __restrict__ W1,
            const float* __restrict__ W2, const float* __restrict__ W3,
            __bf16* __restrict__ out, __bf16* __restrict__ out2)
{
    const float* src[4] = {W0, W1, W2, W3};
    const int z = blockIdx.y;
    const size_t idx = ((size_t)blockIdx.x * 256 + threadIdx.x) * 4;
    const float4 v = *(const float4*)&src[z][idx];
    if (z == 3) {
        bf16x8 o;
        o[0] = (__bf16)v.x; o[1] = (__bf16)v.x;
        o[2] = (__bf16)v.y; o[3] = (__bf16)v.y;
        o[4] = (__bf16)v.z; o[5] = (__bf16)v.z;
        o[6] = (__bf16)v.w; o[7] = (__bf16)v.w;
        *(bf16x8*)&out2[idx * 2] = o;
    } else {
        bf16x4 o;
        o[0] = (__bf16)v.x; o[1] = (__bf16)v.y; o[2] = (__bf16)v.z; o[3] = (__bf16)v.w;
        *(bf16x4*)&out[(size_t)z * Dc * Dc + idx] = o;
    }
}

// ---------------------------------------------------------------------------
// Activation cast: Abf[z] = RNE bf16 of {query,key,value}, 8 elems/thread.
// ---------------------------------------------------------------------------
__global__ __launch_bounds__(256)
void acast(const float* __restrict__ A0, const float* __restrict__ A1,
           const float* __restrict__ A2, __bf16* __restrict__ out)
{
    const float* src[3] = {A0, A1, A2};
    const int z = blockIdx.y;
    const size_t idx = ((size_t)blockIdx.x * 256 + threadIdx.x) * 8;
    const float4 a = *(const float4*)&src[z][idx];
    const float4 b = *(const float4*)&src[z][idx + 4];
    bf16x8 o;
    o[0] = (__bf16)a.x; o[1] = (__bf16)a.y; o[2] = (__bf16)a.z; o[3] = (__bf16)a.w;
    o[4] = (__bf16)b.x; o[5] = (__bf16)b.y; o[6] = (__bf16)b.z; o[7] = (__bf16)b.w;
    *(bf16x8*)&out[(size_t)z * BSc * Dc + idx] = o;
}

// ---------------------------------------------------------------------------
// Pure double-GLDS K-sweep, M-tile 128 (qkv): A and W both bf16 via
// global_load_lds, XOR-swizzled dbuf. One barrier per k-iter.
// ---------------------------------------------------------------------------
template<int KD>
__device__ __forceinline__ void sweep128bb(const __bf16* __restrict__ A,
                                           const __bf16* __restrict__ Wh,
                                           char* AsB, char* WsB,
                                           int gm0, int gn0, f32x4 acc[4][4])
{
    const int tid  = threadIdx.x;
    const int w    = tid >> 6;
    const int lane = tid & 63;
    const int cc   = lane & 15;
    const int g    = lane >> 4;
    const int wm   = (w & 1) * 64;
    const int wn   = (w >> 1) * 64;

    int wrow[4], wchk[4];
#pragma unroll
    for (int r = 0; r < 4; ++r) {
        const int L = r * 256 + tid;
        wrow[r] = L >> 3;
        wchk[r] = (L & 7) ^ (wrow[r] & 7);
    }

    // ---- prologue: stage tile 0 into buf 0 ----
#pragma unroll
    for (int r = 0; r < 4; ++r) {
        GLDS16(Wh + (size_t)(gn0 + wrow[r]) * KD + wchk[r] * 8,
               WsB + (r * 256 + tid) * 16);
        GLDS16(A + (size_t)(gm0 + wrow[r]) * KD + wchk[r] * 8,
               AsB + (r * 256 + tid) * 16);
    }

    for (int it = 0; it < KD / 64; ++it) {
        const char* As = AsB + (it & 1) * 16384;
        const char* Ws = WsB + (it & 1) * 16384;
        __syncthreads();   // drains tile-it GLDS (issued last iter)

        if (it + 1 < KD / 64) {
            const int kn = (it + 1) * 64;
            char* Wn = WsB + ((it + 1) & 1) * 16384;
            char* An = AsB + ((it + 1) & 1) * 16384;
#pragma unroll
            for (int r = 0; r < 4; ++r) {
                GLDS16(Wh + (size_t)(gn0 + wrow[r]) * KD + kn + wchk[r] * 8,
                       Wn + (r * 256 + tid) * 16);
                GLDS16(A + (size_t)(gm0 + wrow[r]) * KD + kn + wchk[r] * 8,
                       An + (r * 256 + tid) * 16);
            }
        }

        // ---- compute tile it ----
        __builtin_amdgcn_s_setprio(1);
#pragma unroll
        for (int kk = 0; kk < 2; ++kk) {
            const int cb4 = (kk * 4 + g) << 4;
            bf16x8 af[4], bfr[4];
#pragma unroll
            for (int mt = 0; mt < 4; ++mt) {
                const int row = wm + mt * 16 + cc;
                af[mt] = *(const bf16x8*)(As + row * 128 + (cb4 ^ ((row & 7) << 4)));
            }
#pragma unroll
            for (int nt = 0; nt < 4; ++nt) {
                const int row = wn + nt * 16 + cc;
                bfr[nt] = *(const bf16x8*)(Ws + row * 128 + (cb4 ^ ((row & 7) << 4)));
            }
#pragma unroll
            for (int mt = 0; mt < 4; ++mt)
#pragma unroll
                for (int nt = 0; nt < 4; ++nt)
                    acc[mt][nt] = __builtin_amdgcn_mfma_f32_16x16x32_bf16(
                        af[mt], bfr[nt], acc[mt][nt], 0, 0, 0);
        }
        __builtin_amdgcn_s_setprio(0);
    }
}

// ---------------------------------------------------------------------------
// Double-GLDS K-sweep, M-tile 64 (out projection): W dbuf 32K + A dbuf 16K.
// ---------------------------------------------------------------------------
template<int KD>
__device__ __forceinline__ void sweep64bb(const __bf16* __restrict__ A,
                                          const __bf16* __restrict__ Wh,
                                          char* AsB, char* WsB,
                                          int gm0, int gn0, f32x4 acc[2][4])
{
    const int tid  = threadIdx.x;
    const int w    = tid >> 6;
    const int lane = tid & 63;
    const int cc   = lane & 15;
    const int g    = lane >> 4;
    const int wm   = (w & 1) * 32;
    const int wn   = (w >> 1) * 64;

    int wrow[4], wchk[4];
#pragma unroll
    for (int r = 0; r < 4; ++r) {
        const int L = r * 256 + tid;
        wrow[r] = L >> 3;
        wchk[r] = (L & 7) ^ (wrow[r] & 7);
    }
    int arow[2], achk[2];
#pragma unroll
    for (int r = 0; r < 2; ++r) {
        const int L = r * 256 + tid;
        arow[r] = L >> 3;
        achk[r] = (L & 7) ^ (arow[r] & 7);
    }

    // ---- prologue: tile 0 -> buf 0 ----
#pragma unroll
    for (int r = 0; r < 4; ++r)
        GLDS16(Wh + (size_t)(gn0 + wrow[r]) * KD + wchk[r] * 8,
               WsB + (r * 256 + tid) * 16);
#pragma unroll
    for (int r = 0; r < 2; ++r)
        GLDS16(A + (size_t)(gm0 + arow[r]) * KD + achk[r] * 8,
               AsB + (r * 256 + tid) * 16);

    for (int it = 0; it < KD / 64; ++it) {
        const char* As = AsB + (it & 1) * 8192;
        const char* Ws = WsB + (it & 1) * 16384;
        __syncthreads();

        if (it + 1 < KD / 64) {
            const int kn = (it + 1) * 64;
            char* Wn = WsB + ((it + 1) & 1) * 16384;
            char* An = AsB + ((it + 1) & 1) * 8192;
#pragma unroll
            for (int r = 0; r < 4; ++r)
                GLDS16(Wh + (size_t)(gn0 + wrow[r]) * KD + kn + wchk[r] * 8,
                       Wn + (r * 256 + tid) * 16);
#pragma unroll
            for (int r = 0; r < 2; ++r)
                GLDS16(A + (size_t)(gm0 + arow[r]) * KD + kn + achk[r] * 8,
                       An + (r * 256 + tid) * 16);
        }

        __builtin_amdgcn_s_setprio(1);
#pragma unroll
        for (int kk = 0; kk < 2; ++kk) {
            const int cb4 = (kk * 4 + g) << 4;
            bf16x8 af[2], bfr[4];
#pragma unroll
            for (int mt = 0; mt < 2; ++mt) {
                const int row = wm + mt * 16 + cc;
                af[mt] = *(const bf16x8*)(As + row * 128 + (cb4 ^ ((row & 7) << 4)));
            }
#pragma unroll
            for (int nt = 0; nt < 4; ++nt) {
                const int row = wn + nt * 16 + cc;
                bfr[nt] = *(const bf16x8*)(Ws + row * 128 + (cb4 ^ ((row & 7) << 4)));
            }
#pragma unroll
            for (int mt = 0; mt < 2; ++mt)
#pragma unroll
                for (int nt = 0; nt < 4; ++nt)
                    acc[mt][nt] = __builtin_amdgcn_mfma_f32_16x16x32_bf16(
                        af[mt], bfr[nt], acc[mt][nt], 0, 0, 0);
        }
        __builtin_amdgcn_s_setprio(0);
    }
}

// ---------------------------------------------------------------------------
// QKV projection (double-GLDS). z==2 writes V^T [BH,DH,S] directly.
// ---------------------------------------------------------------------------
__global__ __launch_bounds__(256)
void qkv_mfma(const __bf16* __restrict__ Abf, const __bf16* __restrict__ Whi,
              const float* __restrict__ bq, const float* __restrict__ bk,
              const float* __restrict__ bv,
              __bf16* __restrict__ Qo, __bf16* __restrict__ Ko, __bf16* __restrict__ Vt)
{
    __shared__ __align__(16) char smem[65536];   // A dbuf 32K | W dbuf 32K

    const int z = blockIdx.z;
    const float* bias = (z == 0) ? bq : (z == 1) ? bk : bv;
    const float scale = (z == 0) ? 0.125f * LOG2E : 1.0f;
    const __bf16* A   = Abf + (size_t)z * BSc * Dc;
    const __bf16* Wh  = Whi + (size_t)z * Dc * Dc;

    const int gm0 = blockIdx.x * 128;
    const int gn0 = blockIdx.y * 128;

    f32x4 acc[4][4];
#pragma unroll
    for (int mt = 0; mt < 4; ++mt)
#pragma unroll
        for (int nt = 0; nt < 4; ++nt) acc[mt][nt] = {0.f, 0.f, 0.f, 0.f};

    sweep128bb<Dc>(A, Wh, smem, smem + 32768, gm0, gn0, acc);

    const int tid = threadIdx.x;
    const int w = tid >> 6, lane = tid & 63;
    const int cc = lane & 15, g = lane >> 4;
    const int wm = (w & 1) * 64, wn = (w >> 1) * 64;

    float bias4[4];
#pragma unroll
    for (int nt = 0; nt < 4; ++nt) bias4[nt] = bias[gn0 + wn + nt * 16 + cc];

    if (z == 2) {
#pragma unroll
        for (int mt = 0; mt < 4; ++mt)
#pragma unroll
            for (int nt = 0; nt < 4; ++nt) {
                const int col = gn0 + wn + nt * 16 + cc;
                const int h = col >> 6, dh = col & 63;
                const int row0 = gm0 + wm + mt * 16 + g * 4;
                const int b = row0 >> 11, s0 = row0 & 2047;
                bf16x4 vv;
#pragma unroll
                for (int reg = 0; reg < 4; ++reg)
                    vv[reg] = (__bf16)(acc[mt][nt][reg] + bias4[nt]);
                *(bf16x4*)&Vt[(((size_t)(b * Hc + h)) * DHc + dh) * Sc + s0] = vv;
            }
    } else {
        __bf16* O = (z == 0) ? Qo : Ko;
#pragma unroll
        for (int mt = 0; mt < 4; ++mt)
#pragma unroll
            for (int nt = 0; nt < 4; ++nt) {
                const int col = gn0 + wn + nt * 16 + cc;
                const int h = col >> 6, dh = col & 63;
#pragma unroll
                for (int reg = 0; reg < 4; ++reg) {
                    const int row = gm0 + wm + mt * 16 + g * 4 + reg;
                    const int b = row >> 11, s = row & 2047;
                    O[(((size_t)(b * Hc + h)) * Sc + s) * DHc + dh] =
                        (__bf16)((acc[mt][nt][reg] + bias4[nt]) * scale);
                }
            }
    }
}

// ---------------------------------------------------------------------------
// Output projection: out = ctx2 @ Wo2^T + bo (K=2048 interleaved hi/lo).
// M64xN128, 512 blocks = 2/CU.
// ---------------------------------------------------------------------------
__global__ __launch_bounds__(256)
void out_mfma(const __bf16* __restrict__ ctx2, const __bf16* __restrict__ Wo2,
              const float* __restrict__ bo, float* __restrict__ out)
{
    __shared__ __align__(16) char smem[49152];   // W dbuf 32K | A dbuf 16K

    const int gm0 = blockIdx.x * 64;
    const int gn0 = blockIdx.y * 128;

    f32x4 acc[2][4];
#pragma unroll
    for (int mt = 0; mt < 2; ++mt)
#pragma unroll
        for (int nt = 0; nt < 4; ++nt) acc[mt][nt] = {0.f, 0.f, 0.f, 0.f};

    sweep64bb<2 * Dc>(ctx2, Wo2, smem + 32768, smem, gm0, gn0, acc);

    const int tid = threadIdx.x;
    const int w = tid >> 6, lane = tid & 63;
    const int cc = lane & 15, g = lane >> 4;
    const int wm = (w & 1) * 32, wn = (w >> 1) * 64;

    float bias4[4];
#pragma unroll
    for (int nt = 0; nt < 4; ++nt) bias4[nt] = bo[gn0 + wn + nt * 16 + cc];

#pragma unroll
    for (int mt = 0; mt < 2; ++mt)
#pragma unroll
        for (int nt = 0; nt < 4; ++nt) {
            const int col = gn0 + wn + nt * 16 + cc;
#pragma unroll
            for (int reg = 0; reg < 4; ++reg) {
                const int row = gm0 + wm + mt * 16 + g * 4 + reg;
                out[(size_t)row * Dc + col] = acc[mt][nt][reg] + bias4[nt];
            }
        }
}

// ---------------------------------------------------------------------------
// Bitpack mask: each wave packs 4 u64 words (256 elements).
// ---------------------------------------------------------------------------
__global__ __launch_bounds__(256)
void mask_pack(const int* __restrict__ mask, unsigned long long* __restrict__ out)
{
    const int lane = threadIdx.x & 63;
    const size_t waveBase = ((size_t)blockIdx.x * 4 + (threadIdx.x >> 6)) * 256;
    unsigned long long b0 = __ballot(mask[waveBase + lane]        != 0);
    unsigned long long b1 = __ballot(mask[waveBase + 64 + lane]   != 0);
    unsigned long long b2 = __ballot(mask[waveBase + 128 + lane]  != 0);
    unsigned long long b3 = __ballot(mask[waveBase + 192 + lane]  != 0);
    if (lane == 0) {
        unsigned long long* dst = out + (waveBase >> 6);
        dst[0] = b0; dst[1] = b1; dst[2] = b2; dst[3] = b3;
    }
}

// ---------------------------------------------------------------------------
// Flash attention: 32x32x16 MFMA, swapped QK^T (P[k][q] in-register),
// in-register softmax, P->PV A-frags via cvt-pack + v_permlane32_swap.
// R15: split accumulation chains (z0/z1 per nt, o/o2 merged in epilogue)
// for 2x MFMA ILP. 4 waves x 32 q = 128 q/block, grid 16x32 = 512 blocks.
// ---------------------------------------------------------------------------
__global__ __launch_bounds__(256, 2)
void attn_mfma(const __bf16* __restrict__ Q, const __bf16* __restrict__ K,
               const __bf16* __restrict__ Vt,
               const unsigned long long* __restrict__ mp,
               __bf16* __restrict__ ctx2)
{
    __shared__ __align__(16) char smem[32768];   // K/V dbuf: 2 x (8K K | 8K V)

    const int tid  = threadIdx.x;
    const int w    = tid >> 6;
    const int lane = tid & 63;
    const int c    = lane & 31;          // 32x32 col / q-row / k-row index
    const int u    = lane >> 5;          // half-wave
    const int bh   = blockIdx.y;
    const int b    = bh >> 4;
    const int h    = bh & 15;
    const int qw   = blockIdx.x * 128 + w * 32;   // 32 q-rows per wave

    const __bf16* Qb  = Q  + (size_t)bh * Sc * DHc;
    const __bf16* Kb  = K  + (size_t)bh * Sc * DHc;
    const __bf16* Vtb = Vt + (size_t)bh * DHc * Sc;

    // Q fragments (B-operand of swapped QK^T): qa[ch] = Q[qw+c][16ch+8u .. +7]
    bf16x8 qa[4];
#pragma unroll
    for (int ch = 0; ch < 4; ++ch)
        qa[ch] = *(const bf16x8*)&Qb[(size_t)(qw + c) * DHc + ch * 16 + u * 8];

    f32x16 o[2], o2[2];
#pragma unroll
    for (int dt = 0; dt < 2; ++dt)
#pragma unroll
        for (int i = 0; i < 16; ++i) { o[dt][i] = 0.f; o2[dt][i] = 0.f; }
    float lp[4] = {0.f, 0.f, 0.f, 0.f};

    // staging: identity rows, XOR-swizzled 16B granules
    const int ci[2] = {tid, 256 + tid};
    int rowi[2], ski[2];
#pragma unroll
    for (int i = 0; i < 2; ++i) {
        rowi[i] = ci[i] >> 3;
        ski[i]  = (ci[i] & 7) ^ (rowi[i] & 7);
    }

#pragma unroll
    for (int i = 0; i < 2; ++i) {
        GLDS16(Kb + (size_t)rowi[i] * DHc + ski[i] * 8,
               smem + ci[i] * 16);
        GLDS16(Vtb + (size_t)rowi[i] * Sc + ski[i] * 8,
               smem + 8192 + ci[i] * 16);
    }

    for (int it = 0; it < 32; ++it) {
        const char* Ks = smem + (it & 1) * 16384;
        const char* Vs = Ks + 8192;

        __syncthreads();

        if (it + 1 < 32) {
            char* Kn = smem + ((it + 1) & 1) * 16384;
            const int kn = (it + 1) * 64;
#pragma unroll
            for (int i = 0; i < 2; ++i) {
                GLDS16(Kb + (size_t)(kn + rowi[i]) * DHc + ski[i] * 8,
                       Kn + ci[i] * 16);
                GLDS16(Vtb + (size_t)rowi[i] * Sc + kn + ski[i] * 8,
                       Kn + 8192 + ci[i] * 16);
            }
        }

        // one mask word per lane: q = qw + c, 64 k-bits of this tile
        const unsigned long long mw =
            mp[((size_t)(b * Sc + qw + c) << 5) + it];

        // ---- QK^T (swapped): sc[nt] = K[32nt..+31] . Q^T  -> P[k][q=c] ----
        // split into two independent 2-deep chains per nt
        f32x16 sc[2];
        __builtin_amdgcn_s_setprio(1);
#pragma unroll
        for (int nt = 0; nt < 2; ++nt) {
            f32x16 z0, z1;
#pragma unroll
            for (int i = 0; i < 16; ++i) { z0[i] = -24.f; z1[i] = 0.f; }
            const int row = nt * 32 + c;
            const int rx  = (row & 7) << 4;
            const bf16x8 kb0 = *(const bf16x8*)(Ks + row * 128 + ((0  + u * 16) ^ rx));
            const bf16x8 kb1 = *(const bf16x8*)(Ks + row * 128 + ((32 + u * 16) ^ rx));
            const bf16x8 kb2 = *(const bf16x8*)(Ks + row * 128 + ((64 + u * 16) ^ rx));
            const bf16x8 kb3 = *(const bf16x8*)(Ks + row * 128 + ((96 + u * 16) ^ rx));
            z0 = __builtin_amdgcn_mfma_f32_32x32x16_bf16(kb0, qa[0], z0, 0, 0, 0);
            z1 = __builtin_amdgcn_mfma_f32_32x32x16_bf16(kb1, qa[1], z1, 0, 0, 0);
            z0 = __builtin_amdgcn_mfma_f32_32x32x16_bf16(kb2, qa[2], z0, 0, 0, 0);
            z1 = __builtin_amdgcn_mfma_f32_32x32x16_bf16(kb3, qa[3], z1, 0, 0, 0);
            sc[nt] = z0 + z1;
        }
        __builtin_amdgcn_s_setprio(0);

        // ---- softmax in-register; reg i of tile nt is k = 32nt+8(i>>2)+4u+(i&3)
        unsigned pk[2][4][2];
#pragma unroll
        for (int nt = 0; nt < 2; ++nt)
#pragma unroll
            for (int rr = 0; rr < 4; ++rr) {
                const unsigned nib =
                    (unsigned)(mw >> (nt * 32 + rr * 8 + u * 4)) & 0xFu;
                float pv[4];
#pragma unroll
                for (int r = 0; r < 4; ++r) {
                    float p = __builtin_amdgcn_exp2f(sc[nt][rr * 4 + r]);
                    p = (nib & (1u << r)) ? 0.f : p;
                    lp[rr] += p;
                    pv[r] = p;
                }
                bf16x2 t0; t0[0] = (__bf16)pv[0]; t0[1] = (__bf16)pv[1];
                bf16x2 t1; t1[0] = (__bf16)pv[2]; t1[1] = (__bf16)pv[3];
                pk[nt][rr][0] = __builtin_bit_cast(unsigned, t0);
                pk[nt][rr][1] = __builtin_bit_cast(unsigned, t1);
            }

        // ---- redistribute to PV A-frags: one swap fills two words ----
        bf16x8 pa[4];
#pragma unroll
        for (int kc = 0; kc < 4; ++kc) {
            const int nt = kc >> 1;
            const int r0 = (kc & 1) * 2;
            uint32x2 s0 = __builtin_amdgcn_permlane32_swap(
                pk[nt][r0][0], pk[nt][r0 + 1][0], false, false);
            uint32x2 s1 = __builtin_amdgcn_permlane32_swap(
                pk[nt][r0][1], pk[nt][r0 + 1][1], false, false);
            uint32x4 wds;
            wds[0] = s0[0]; wds[1] = s1[0]; wds[2] = s0[1]; wds[3] = s1[1];
            pa[kc] = __builtin_bit_cast(bf16x8, wds);
        }

        // ---- PV: o/o2 two independent chains per dt, merged in epilogue ----
        __builtin_amdgcn_s_setprio(1);
#pragma unroll
        for (int dt = 0; dt < 2; ++dt) {
            const int row = dt * 32 + c;
            const int rx  = (row & 7) << 4;
            const bf16x8 vb0 = *(const bf16x8*)(Vs + row * 128 + ((0  + u * 16) ^ rx));
            const bf16x8 vb1 = *(const bf16x8*)(Vs + row * 128 + ((32 + u * 16) ^ rx));
            const bf16x8 vb2 = *(const bf16x8*)(Vs + row * 128 + ((64 + u * 16) ^ rx));
            const bf16x8 vb3 = *(const bf16x8*)(Vs + row * 128 + ((96 + u * 16) ^ rx));
            o[dt]  = __builtin_amdgcn_mfma_f32_32x32x16_bf16(pa[0], vb0, o[dt],  0, 0, 0);
            o2[dt] = __builtin_amdgcn_mfma_f32_32x32x16_bf16(pa[1], vb1, o2[dt], 0, 0, 0);
            o[dt]  = __builtin_amdgcn_mfma_f32_32x32x16_bf16(pa[2], vb2, o[dt],  0, 0, 0);
            o2[dt] = __builtin_amdgcn_mfma_f32_32x32x16_bf16(pa[3], vb3, o2[dt], 0, 0, 0);
        }
        __builtin_amdgcn_s_setprio(0);
    }

    // ---- epilogue: merge chains, normalize, write interleaved ctx2 ----
    float lsum = (lp[0] + lp[1]) + (lp[2] + lp[3]);
    lsum += __shfl_xor(lsum, 32);
    const float linv = 1.0f / lsum;

    float inv[16];
#pragma unroll
    for (int i = 0; i < 16; ++i)
        inv[i] = __shfl(linv, (i & 3) + 8 * (i >> 2) + 4 * u);

#pragma unroll
    for (int dt = 0; dt < 2; ++dt)
#pragma unroll
        for (int i = 0; i < 16; ++i) {
            const int q = qw + (i & 3) + 8 * (i >> 2) + 4 * u;
            const int col = h * 64 + dt * 32 + c;
            const float v = (o[dt][i] + o2[dt][i]) * inv[i];
            const __bf16 hi = (__bf16)v;
            bf16x2 hv;
            hv[0] = hi;
            hv[1] = (__bf16)(v - (float)hi);
            *(bf16x2*)&ctx2[(((size_t)b * Sc + q) * Dc + col) * 2] = hv;
        }
}

extern "C" void kernel_launch(void* const* d_in, const int* in_sizes, int n_in,
                              void* d_out, int out_size, void* d_ws, size_t ws_size,
                              hipStream_t stream)
{
    const float* key   = (const float*)d_in[0];
    const float* value = (const float*)d_in[1];
    const float* query = (const float*)d_in[2];
    const int*   mask  = (const int*)  d_in[3];
    const float* Wq    = (const float*)d_in[4];
    const float* bq    = (const float*)d_in[5];
    const float* Wk    = (const float*)d_in[6];
    const float* bk    = (const float*)d_in[7];
    const float* Wv    = (const float*)d_in[8];
    const float* bv    = (const float*)d_in[9];
    const float* Wo    = (const float*)d_in[10];
    const float* bo    = (const float*)d_in[11];
    float* out = (float*)d_out;

    char* wsb = (char*)d_ws;
    __bf16* Qbf  = (__bf16*)(wsb);                                 // 8 MB
    __bf16* Kbf  = (__bf16*)(wsb + ((size_t)8  << 20));            // 8 MB
    __bf16* Vt   = (__bf16*)(wsb + ((size_t)16 << 20));            // 8 MB
    unsigned long long* mpk = (unsigned long long*)(wsb + ((size_t)24 << 20)); // 1 MB
    __bf16* Whi  = (__bf16*)(wsb + ((size_t)25 << 20));            // 6 MB (Wq,Wk,Wv)
    __bf16* Wo2  = (__bf16*)(wsb + ((size_t)31 << 20));            // 4 MB
    __bf16* ctx2 = (__bf16*)(wsb + ((size_t)35 << 20));            // 16 MB
    __bf16* Abf  = (__bf16*)(wsb + ((size_t)51 << 20));            // 24 MB

    dim3 gws(Dc * Dc / (256 * 4), 4);
    wsplit<<<gws, 256, 0, stream>>>(Wq, Wk, Wv, Wo, Whi, Wo2);

    dim3 gac(BSc * Dc / (256 * 8), 3);
    acast<<<gac, 256, 0, stream>>>(query, key, value, Abf);

    dim3 gqkv(BSc / 128, Dc / 128, 3);
    qkv_mfma<<<gqkv, 256, 0, stream>>>(Abf, Whi, bq, bk, bv, Qbf, Kbf, Vt);

    const int mask_n = Bc * Sc * Sc;
    mask_pack<<<mask_n / 1024, 256, 0, stream>>>(mask, mpk);

    dim3 gattn(Sc / 128, Bc * Hc);
    attn_mfma<<<gattn, 256, 0, stream>>>(Qbf, Kbf, Vt, mpk, ctx2);

    dim3 gout(BSc / 64, Dc / 128);
    out_mfma<<<gout, 256, 0, stream>>>(ctx2, Wo2, bo, out);
}

// Round 8
// 263.611 us; speedup vs baseline: 1.0169x; 1.0144x over previous
//
#include <hip/hip_runtime.h>
#include <math.h>

// MultiHeadedAttention  B=2, S=2048, D=1024, H=16, DH=64 (fp32 in/out)
// R18 == R16/R17 algorithm, delambdafied (container failed twice on that
// binary; free-function restructure perturbs codegen; schedule identical):
//  - attn: depth-2 software pipeline, 3 K/V LDS buffers (48KB). Phase t:
//    barrier -> STAGE(t+2) -> QK(t+1) [MFMA] -> SMPV(t) [VALU+MFMA], so
//    QK(t+1) issue overlaps SM(t) VALU. sc/mask in named regs, even/odd
//    static unroll. 32x32x16 swapped QK^T, in-register softmax, permlane.
//  - out_mfma: XCD-chunked 8x8 supertile raster (1D grid 512).
// qkv/acast/wsplit/mask_pack unchanged from R15.
// ws: Qbf@0 Kbf@8M Vt@16M mpk@24M Whi@25M Wo2@31M ctx2@35M Abf@51M (75MB)

constexpr int Bc  = 2;
constexpr int Sc  = 2048;
constexpr int Dc  = 1024;
constexpr int Hc  = 16;
constexpr int DHc = 64;
constexpr int BSc = Bc * Sc;     // 4096

constexpr float LOG2E = 1.4426950408889634f;

typedef __bf16 bf16x8 __attribute__((ext_vector_type(8)));
typedef __bf16 bf16x4 __attribute__((ext_vector_type(4)));
typedef __bf16 bf16x2 __attribute__((ext_vector_type(2)));
typedef float  f32x4  __attribute__((ext_vector_type(4)));
typedef float  f32x16 __attribute__((ext_vector_type(16)));
typedef unsigned uint32x2 __attribute__((ext_vector_type(2)));
typedef unsigned uint32x4 __attribute__((ext_vector_type(4)));

#define GLDS16(gp, lp) __builtin_amdgcn_global_load_lds( \
    (const __attribute__((address_space(1))) void*)(gp), \
    (__attribute__((address_space(3))) void*)(lp), 16, 0, 0)

// ---------------------------------------------------------------------------
// Weight cast: z<3 -> Whi[z] = RNE bf16 of {Wq,Wk,Wv}; z==3 -> Wo2 with each
// weight duplicated into (hi,lo) interleaved slots.
// ---------------------------------------------------------------------------
__global__ __launch_bounds__(256)
void wsplit(const float* __restrict__ W0, const float* __restrict__ W1,
            const float* __restrict__ W2, const float* __restrict__ W3,
            __bf16* __restrict__ out, __bf16* __restrict__ out2)
{
    const float* src[4] = {W0, W1, W2, W3};
    const int z = blockIdx.y;
    const size_t idx = ((size_t)blockIdx.x * 256 + threadIdx.x) * 4;
    const float4 v = *(const float4*)&src[z][idx];
    if (z == 3) {
        bf16x8 o;
        o[0] = (__bf16)v.x; o[1] = (__bf16)v.x;
        o[2] = (__bf16)v.y; o[3] = (__bf16)v.y;
        o[4] = (__bf16)v.z; o[5] = (__bf16)v.z;
        o[6] = (__bf16)v.w; o[7] = (__bf16)v.w;
        *(bf16x8*)&out2[idx * 2] = o;
    } else {
        bf16x4 o;
        o[0] = (__bf16)v.x; o[1] = (__bf16)v.y; o[2] = (__bf16)v.z; o[3] = (__bf16)v.w;
        *(bf16x4*)&out[(size_t)z * Dc * Dc + idx] = o;
    }
}

// ---------------------------------------------------------------------------
// Activation cast: Abf[z] = RNE bf16 of {query,key,value}, 8 elems/thread.
// ---------------------------------------------------------------------------
__global__ __launch_bounds__(256)
void acast(const float* __restrict__ A0, const float* __restrict__ A1,
           const float* __restrict__ A2, __bf16* __restrict__ out)
{
    const float* src[3] = {A0, A1, A2};
    const int z = blockIdx.y;
    const size_t idx = ((size_t)blockIdx.x * 256 + threadIdx.x) * 8;
    const float4 a = *(const float4*)&src[z][idx];
    const float4 b = *(const float4*)&src[z][idx + 4];
    bf16x8 o;
    o[0] = (__bf16)a.x; o[1] = (__bf16)a.y; o[2] = (__bf16)a.z; o[3] = (__bf16)a.w;
    o[4] = (__bf16)b.x; o[5] = (__bf16)b.y; o[6] = (__bf16)b.z; o[7] = (__bf16)b.w;
    *(bf16x8*)&out[(size_t)z * BSc * Dc + idx] = o;
}

// ---------------------------------------------------------------------------
// Pure double-GLDS K-sweep, M-tile 128 (qkv).
// ---------------------------------------------------------------------------
template<int KD>
__device__ __forceinline__ void sweep128bb(const __bf16* __restrict__ A,
                                           const __bf16* __restrict__ Wh,
                                           char* AsB, char* WsB,
                                           int gm0, int gn0, f32x4 acc[4][4])
{
    const int tid  = threadIdx.x;
    const int w    = tid >> 6;
    const int lane = tid & 63;
    const int cc   = lane & 15;
    const int g    = lane >> 4;
    const int wm   = (w & 1) * 64;
    const int wn   = (w >> 1) * 64;

    int wrow[4], wchk[4];
#pragma unroll
    for (int r = 0; r < 4; ++r) {
        const int L = r * 256 + tid;
        wrow[r] = L >> 3;
        wchk[r] = (L & 7) ^ (wrow[r] & 7);
    }

#pragma unroll
    for (int r = 0; r < 4; ++r) {
        GLDS16(Wh + (size_t)(gn0 + wrow[r]) * KD + wchk[r] * 8,
               WsB + (r * 256 + tid) * 16);
        GLDS16(A + (size_t)(gm0 + wrow[r]) * KD + wchk[r] * 8,
               AsB + (r * 256 + tid) * 16);
    }

    for (int it = 0; it < KD / 64; ++it) {
        const char* As = AsB + (it & 1) * 16384;
        const char* Ws = WsB + (it & 1) * 16384;
        __syncthreads();

        if (it + 1 < KD / 64) {
            const int kn = (it + 1) * 64;
            char* Wn = WsB + ((it + 1) & 1) * 16384;
            char* An = AsB + ((it + 1) & 1) * 16384;
#pragma unroll
            for (int r = 0; r < 4; ++r) {
                GLDS16(Wh + (size_t)(gn0 + wrow[r]) * KD + kn + wchk[r] * 8,
                       Wn + (r * 256 + tid) * 16);
                GLDS16(A + (size_t)(gm0 + wrow[r]) * KD + kn + wchk[r] * 8,
                       An + (r * 256 + tid) * 16);
            }
        }

        __builtin_amdgcn_s_setprio(1);
#pragma unroll
        for (int kk = 0; kk < 2; ++kk) {
            const int cb4 = (kk * 4 + g) << 4;
            bf16x8 af[4], bfr[4];
#pragma unroll
            for (int mt = 0; mt < 4; ++mt) {
                const int row = wm + mt * 16 + cc;
                af[mt] = *(const bf16x8*)(As + row * 128 + (cb4 ^ ((row & 7) << 4)));
            }
#pragma unroll
            for (int nt = 0; nt < 4; ++nt) {
                const int row = wn + nt * 16 + cc;
                bfr[nt] = *(const bf16x8*)(Ws + row * 128 + (cb4 ^ ((row & 7) << 4)));
            }
#pragma unroll
            for (int mt = 0; mt < 4; ++mt)
#pragma unroll
                for (int nt = 0; nt < 4; ++nt)
                    acc[mt][nt] = __builtin_amdgcn_mfma_f32_16x16x32_bf16(
                        af[mt], bfr[nt], acc[mt][nt], 0, 0, 0);
        }
        __builtin_amdgcn_s_setprio(0);
    }
}

// ---------------------------------------------------------------------------
// Double-GLDS K-sweep, M-tile 64 (out projection): W dbuf 32K + A dbuf 16K.
// ---------------------------------------------------------------------------
template<int KD>
__device__ __forceinline__ void sweep64bb(const __bf16* __restrict__ A,
                                          const __bf16* __restrict__ Wh,
                                          char* AsB, char* WsB,
                                          int gm0, int gn0, f32x4 acc[2][4])
{
    const int tid  = threadIdx.x;
    const int w    = tid >> 6;
    const int lane = tid & 63;
    const int cc   = lane & 15;
    const int g    = lane >> 4;
    const int wm   = (w & 1) * 32;
    const int wn   = (w >> 1) * 64;

    int wrow[4], wchk[4];
#pragma unroll
    for (int r = 0; r < 4; ++r) {
        const int L = r * 256 + tid;
        wrow[r] = L >> 3;
        wchk[r] = (L & 7) ^ (wrow[r] & 7);
    }
    int arow[2], achk[2];
#pragma unroll
    for (int r = 0; r < 2; ++r) {
        const int L = r * 256 + tid;
        arow[r] = L >> 3;
        achk[r] = (L & 7) ^ (arow[r] & 7);
    }

#pragma unroll
    for (int r = 0; r < 4; ++r)
        GLDS16(Wh + (size_t)(gn0 + wrow[r]) * KD + wchk[r] * 8,
               WsB + (r * 256 + tid) * 16);
#pragma unroll
    for (int r = 0; r < 2; ++r)
        GLDS16(A + (size_t)(gm0 + arow[r]) * KD + achk[r] * 8,
               AsB + (r * 256 + tid) * 16);

    for (int it = 0; it < KD / 64; ++it) {
        const char* As = AsB + (it & 1) * 8192;
        const char* Ws = WsB + (it & 1) * 16384;
        __syncthreads();

        if (it + 1 < KD / 64) {
            const int kn = (it + 1) * 64;
            char* Wn = WsB + ((it + 1) & 1) * 16384;
            char* An = AsB + ((it + 1) & 1) * 8192;
#pragma unroll
            for (int r = 0; r < 4; ++r)
                GLDS16(Wh + (size_t)(gn0 + wrow[r]) * KD + kn + wchk[r] * 8,
                       Wn + (r * 256 + tid) * 16);
#pragma unroll
            for (int r = 0; r < 2; ++r)
                GLDS16(A + (size_t)(gm0 + arow[r]) * KD + kn + achk[r] * 8,
                       An + (r * 256 + tid) * 16);
        }

        __builtin_amdgcn_s_setprio(1);
#pragma unroll
        for (int kk = 0; kk < 2; ++kk) {
            const int cb4 = (kk * 4 + g) << 4;
            bf16x8 af[2], bfr[4];
#pragma unroll
            for (int mt = 0; mt < 2; ++mt) {
                const int row = wm + mt * 16 + cc;
                af[mt] = *(const bf16x8*)(As + row * 128 + (cb4 ^ ((row & 7) << 4)));
            }
#pragma unroll
            for (int nt = 0; nt < 4; ++nt) {
                const int row = wn + nt * 16 + cc;
                bfr[nt] = *(const bf16x8*)(Ws + row * 128 + (cb4 ^ ((row & 7) << 4)));
            }
#pragma unroll
            for (int mt = 0; mt < 2; ++mt)
#pragma unroll
                for (int nt = 0; nt < 4; ++nt)
                    acc[mt][nt] = __builtin_amdgcn_mfma_f32_16x16x32_bf16(
                        af[mt], bfr[nt], acc[mt][nt], 0, 0, 0);
        }
        __builtin_amdgcn_s_setprio(0);
    }
}

// ---------------------------------------------------------------------------
// QKV projection (double-GLDS). z==2 writes V^T [BH,DH,S] directly.
// ---------------------------------------------------------------------------
__global__ __launch_bounds__(256)
void qkv_mfma(const __bf16* __restrict__ Abf, const __bf16* __restrict__ Whi,
              const float* __restrict__ bq, const float* __restrict__ bk,
              const float* __restrict__ bv,
              __bf16* __restrict__ Qo, __bf16* __restrict__ Ko, __bf16* __restrict__ Vt)
{
    __shared__ __align__(16) char smem[65536];   // A dbuf 32K | W dbuf 32K

    const int z = blockIdx.z;
    const float* bias = (z == 0) ? bq : (z == 1) ? bk : bv;
    const float scale = (z == 0) ? 0.125f * LOG2E : 1.0f;
    const __bf16* A   = Abf + (size_t)z * BSc * Dc;
    const __bf16* Wh  = Whi + (size_t)z * Dc * Dc;

    const int gm0 = blockIdx.x * 128;
    const int gn0 = blockIdx.y * 128;

    f32x4 acc[4][4];
#pragma unroll
    for (int mt = 0; mt < 4; ++mt)
#pragma unroll
        for (int nt = 0; nt < 4; ++nt) acc[mt][nt] = {0.f, 0.f, 0.f, 0.f};

    sweep128bb<Dc>(A, Wh, smem, smem + 32768, gm0, gn0, acc);

    const int tid = threadIdx.x;
    const int w = tid >> 6, lane = tid & 63;
    const int cc = lane & 15, g = lane >> 4;
    const int wm = (w & 1) * 64, wn = (w >> 1) * 64;

    float bias4[4];
#pragma unroll
    for (int nt = 0; nt < 4; ++nt) bias4[nt] = bias[gn0 + wn + nt * 16 + cc];

    if (z == 2) {
#pragma unroll
        for (int mt = 0; mt < 4; ++mt)
#pragma unroll
            for (int nt = 0; nt < 4; ++nt) {
                const int col = gn0 + wn + nt * 16 + cc;
                const int h = col >> 6, dh = col & 63;
                const int row0 = gm0 + wm + mt * 16 + g * 4;
                const int b = row0 >> 11, s0 = row0 & 2047;
                bf16x4 vv;
#pragma unroll
                for (int reg = 0; reg < 4; ++reg)
                    vv[reg] = (__bf16)(acc[mt][nt][reg] + bias4[nt]);
                *(bf16x4*)&Vt[(((size_t)(b * Hc + h)) * DHc + dh) * Sc + s0] = vv;
            }
    } else {
        __bf16* O = (z == 0) ? Qo : Ko;
#pragma unroll
        for (int mt = 0; mt < 4; ++mt)
#pragma unroll
            for (int nt = 0; nt < 4; ++nt) {
                const int col = gn0 + wn + nt * 16 + cc;
                const int h = col >> 6, dh = col & 63;
#pragma unroll
                for (int reg = 0; reg < 4; ++reg) {
                    const int row = gm0 + wm + mt * 16 + g * 4 + reg;
                    const int b = row >> 11, s = row & 2047;
                    O[(((size_t)(b * Hc + h)) * Sc + s) * DHc + dh] =
                        (__bf16)((acc[mt][nt][reg] + bias4[nt]) * scale);
                }
            }
    }
}

// ---------------------------------------------------------------------------
// Output projection: out = ctx2 @ Wo2^T + bo (K=2048 interleaved hi/lo).
// M64xN128; XCD-chunked 8x8 supertile raster for L2 locality.
// ---------------------------------------------------------------------------
__global__ __launch_bounds__(256)
void out_mfma(const __bf16* __restrict__ ctx2, const __bf16* __restrict__ Wo2,
              const float* __restrict__ bo, float* __restrict__ out)
{
    __shared__ __align__(16) char smem[49152];   // W dbuf 32K | A dbuf 16K

    // bijective raster: XCD-contiguous chunks of 64 blocks, each an
    // 8M x 8N supertile (shares 2MB ctx2 window + 4MB Wo2 in that L2)
    const int lb = (blockIdx.x & 7) * 64 + (blockIdx.x >> 3);
    const int gm0 = ((lb >> 6) * 8 + (lb & 7)) * 64;
    const int gn0 = ((lb >> 3) & 7) * 128;

    f32x4 acc[2][4];
#pragma unroll
    for (int mt = 0; mt < 2; ++mt)
#pragma unroll
        for (int nt = 0; nt < 4; ++nt) acc[mt][nt] = {0.f, 0.f, 0.f, 0.f};

    sweep64bb<2 * Dc>(ctx2, Wo2, smem + 32768, smem, gm0, gn0, acc);

    const int tid = threadIdx.x;
    const int w = tid >> 6, lane = tid & 63;
    const int cc = lane & 15, g = lane >> 4;
    const int wm = (w & 1) * 32, wn = (w >> 1) * 64;

    float bias4[4];
#pragma unroll
    for (int nt = 0; nt < 4; ++nt) bias4[nt] = bo[gn0 + wn + nt * 16 + cc];

#pragma unroll
    for (int mt = 0; mt < 2; ++mt)
#pragma unroll
        for (int nt = 0; nt < 4; ++nt) {
            const int col = gn0 + wn + nt * 16 + cc;
#pragma unroll
            for (int reg = 0; reg < 4; ++reg) {
                const int row = gm0 + wm + mt * 16 + g * 4 + reg;
                out[(size_t)row * Dc + col] = acc[mt][nt][reg] + bias4[nt];
            }
        }
}

// ---------------------------------------------------------------------------
// Bitpack mask: each wave packs 4 u64 words (256 elements).
// ---------------------------------------------------------------------------
__global__ __launch_bounds__(256)
void mask_pack(const int* __restrict__ mask, unsigned long long* __restrict__ out)
{
    const int lane = threadIdx.x & 63;
    const size_t waveBase = ((size_t)blockIdx.x * 4 + (threadIdx.x >> 6)) * 256;
    unsigned long long b0 = __ballot(mask[waveBase + lane]        != 0);
    unsigned long long b1 = __ballot(mask[waveBase + 64 + lane]   != 0);
    unsigned long long b2 = __ballot(mask[waveBase + 128 + lane]  != 0);
    unsigned long long b3 = __ballot(mask[waveBase + 192 + lane]  != 0);
    if (lane == 0) {
        unsigned long long* dst = out + (waveBase >> 6);
        dst[0] = b0; dst[1] = b1; dst[2] = b2; dst[3] = b3;
    }
}

// ---------------------------------------------------------------------------
// attn helpers (plain free functions, no lambda captures)
// ---------------------------------------------------------------------------
__device__ __forceinline__ void stage_kv(const __bf16* Kb, const __bf16* Vtb,
                                         char* B, int kn,
                                         int rowi0, int ski0, int ci0,
                                         int rowi1, int ski1, int ci1)
{
    GLDS16(Kb + (size_t)(kn + rowi0) * DHc + ski0 * 8, B + ci0 * 16);
    GLDS16(Vtb + (size_t)rowi0 * Sc + kn + ski0 * 8, B + 8192 + ci0 * 16);
    GLDS16(Kb + (size_t)(kn + rowi1) * DHc + ski1 * 8, B + ci1 * 16);
    GLDS16(Vtb + (size_t)rowi1 * Sc + kn + ski1 * 8, B + 8192 + ci1 * 16);
}

__device__ __forceinline__ void qk_tile(const char* Ks, const bf16x8 qa[4],
                                        int c, int u, f32x16& s0, f32x16& s1)
{
    __builtin_amdgcn_s_setprio(1);
#pragma unroll
    for (int nt = 0; nt < 2; ++nt) {
        f32x16 z;
#pragma unroll
        for (int i = 0; i < 16; ++i) z[i] = -24.f;
        const int row = nt * 32 + c;
        const int rx  = (row & 7) << 4;
#pragma unroll
        for (int ch = 0; ch < 4; ++ch) {
            const bf16x8 kb = *(const bf16x8*)
                (Ks + row * 128 + ((ch * 32 + u * 16) ^ rx));
            z = __builtin_amdgcn_mfma_f32_32x32x16_bf16(kb, qa[ch], z, 0, 0, 0);
        }
        if (nt == 0) s0 = z; else s1 = z;
    }
    __builtin_amdgcn_s_setprio(0);
}

__device__ __forceinline__ void smpv_tile(const char* Vs,
                                          const f32x16& s0, const f32x16& s1,
                                          unsigned long long mw, int c, int u,
                                          float lp[4], f32x16 o[2])
{
    unsigned pk[2][4][2];
#pragma unroll
    for (int nt = 0; nt < 2; ++nt)
#pragma unroll
        for (int rr = 0; rr < 4; ++rr) {
            const unsigned nib =
                (unsigned)(mw >> (nt * 32 + rr * 8 + u * 4)) & 0xFu;
            float pv[4];
#pragma unroll
            for (int r = 0; r < 4; ++r) {
                float p = __builtin_amdgcn_exp2f(
                    (nt == 0) ? s0[rr * 4 + r] : s1[rr * 4 + r]);
                p = (nib & (1u << r)) ? 0.f : p;
                lp[rr] += p;
                pv[r] = p;
            }
            bf16x2 t0; t0[0] = (__bf16)pv[0]; t0[1] = (__bf16)pv[1];
            bf16x2 t1; t1[0] = (__bf16)pv[2]; t1[1] = (__bf16)pv[3];
            pk[nt][rr][0] = __builtin_bit_cast(unsigned, t0);
            pk[nt][rr][1] = __builtin_bit_cast(unsigned, t1);
        }

    bf16x8 pa[4];
#pragma unroll
    for (int kc = 0; kc < 4; ++kc) {
        const int nt = kc >> 1;
        const int r0 = (kc & 1) * 2;
        uint32x2 w0 = __builtin_amdgcn_permlane32_swap(
            pk[nt][r0][0], pk[nt][r0 + 1][0], false, false);
        uint32x2 w1 = __builtin_amdgcn_permlane32_swap(
            pk[nt][r0][1], pk[nt][r0 + 1][1], false, false);
        uint32x4 wds;
        wds[0] = w0[0]; wds[1] = w1[0]; wds[2] = w0[1]; wds[3] = w1[1];
        pa[kc] = __builtin_bit_cast(bf16x8, wds);
    }

    __builtin_amdgcn_s_setprio(1);
#pragma unroll
    for (int dt = 0; dt < 2; ++dt) {
        const int row = dt * 32 + c;
        const int rx  = (row & 7) << 4;
#pragma unroll
        for (int kc = 0; kc < 4; ++kc) {
            const bf16x8 vb = *(const bf16x8*)
                (Vs + row * 128 + ((kc * 32 + u * 16) ^ rx));
            o[dt] = __builtin_amdgcn_mfma_f32_32x32x16_bf16(pa[kc], vb, o[dt], 0, 0, 0);
        }
    }
    __builtin_amdgcn_s_setprio(0);
}

// ---------------------------------------------------------------------------
// Flash attention: depth-2 pipeline, 3 K/V LDS buffers. Phase t:
// barrier -> STAGE(t+2) -> QK(t+1) -> SMPV(t). Even/odd static unroll.
// 4 waves x 32 q = 128 q/block, grid 16x32.
// ---------------------------------------------------------------------------
__global__ __launch_bounds__(256, 2)
void attn_mfma(const __bf16* __restrict__ Q, const __bf16* __restrict__ K,
               const __bf16* __restrict__ Vt,
               const unsigned long long* __restrict__ mp,
               __bf16* __restrict__ ctx2)
{
    __shared__ __align__(16) char smem[49152];   // 3 x (8K K | 8K V)

    const int tid  = threadIdx.x;
    const int w    = tid >> 6;
    const int lane = tid & 63;
    const int c    = lane & 31;
    const int u    = lane >> 5;
    const int bh   = blockIdx.y;
    const int b    = bh >> 4;
    const int h    = bh & 15;
    const int qw   = blockIdx.x * 128 + w * 32;

    const __bf16* Qb  = Q  + (size_t)bh * Sc * DHc;
    const __bf16* Kb  = K  + (size_t)bh * Sc * DHc;
    const __bf16* Vtb = Vt + (size_t)bh * DHc * Sc;

    bf16x8 qa[4];
#pragma unroll
    for (int ch = 0; ch < 4; ++ch)
        qa[ch] = *(const bf16x8*)&Qb[(size_t)(qw + c) * DHc + ch * 16 + u * 8];

    f32x16 o[2];
#pragma unroll
    for (int dt = 0; dt < 2; ++dt)
#pragma unroll
        for (int i = 0; i < 16; ++i) o[dt][i] = 0.f;
    float lp[4] = {0.f, 0.f, 0.f, 0.f};

    const int ci0 = tid,        ci1 = 256 + tid;
    const int rowi0 = ci0 >> 3, rowi1 = ci1 >> 3;
    const int ski0 = (ci0 & 7) ^ (rowi0 & 7);
    const int ski1 = (ci1 & 7) ^ (rowi1 & 7);

    const size_t mbase = ((size_t)(b * Sc + qw + c) << 5);

    // ---- prologue: stage tiles 0 and 1, drain, QK(0) ----
    stage_kv(Kb, Vtb, smem,         0,  rowi0, ski0, ci0, rowi1, ski1, ci1);
    stage_kv(Kb, Vtb, smem + 16384, 64, rowi0, ski0, ci0, rowi1, ski1, ci1);
    __syncthreads();            // buf0 + buf1 ready

    unsigned long long mwA = mp[mbase + 0], mwB;
    f32x16 sA0, sA1, sB0, sB1;
    qk_tile(smem, qa, c, u, sA0, sA1);      // QK(0) from buf0

    // ---- main loop: 16 even/odd pairs ----
    for (int tp = 0; tp < 16; ++tp) {
        const int t0 = tp * 2;
        // even phase (tile t0): barrier; STAGE(t0+2); QK(t0+1); SMPV(t0)
        __syncthreads();
        if (t0 + 2 < 32)
            stage_kv(Kb, Vtb, smem + ((t0 + 2) % 3) * 16384, (t0 + 2) * 64,
                     rowi0, ski0, ci0, rowi1, ski1, ci1);
        mwB = mp[mbase + (t0 + 1)];
        qk_tile(smem + ((t0 + 1) % 3) * 16384, qa, c, u, sB0, sB1);
        smpv_tile(smem + (t0 % 3) * 16384 + 8192, sA0, sA1, mwA, c, u, lp, o);

        // odd phase (tile t1 = t0+1): barrier; STAGE(t1+2); QK(t1+1); SMPV(t1)
        const int t1 = t0 + 1;
        __syncthreads();
        if (t1 + 2 < 32)
            stage_kv(Kb, Vtb, smem + ((t1 + 2) % 3) * 16384, (t1 + 2) * 64,
                     rowi0, ski0, ci0, rowi1, ski1, ci1);
        if (t1 + 1 < 32) {
            mwA = mp[mbase + (t1 + 1)];
            qk_tile(smem + ((t1 + 1) % 3) * 16384, qa, c, u, sA0, sA1);
        }
        smpv_tile(smem + (t1 % 3) * 16384 + 8192, sB0, sB1, mwB, c, u, lp, o);
    }

    // ---- epilogue ----
    float lsum = (lp[0] + lp[1]) + (lp[2] + lp[3]);
    lsum += __shfl_xor(lsum, 32);
    const float linv = 1.0f / lsum;

    float inv[16];
#pragma unroll
    for (int i = 0; i < 16; ++i)
        inv[i] = __shfl(linv, (i & 3) + 8 * (i >> 2) + 4 * u);

#pragma unroll
    for (int dt = 0; dt < 2; ++dt)
#pragma unroll
        for (int i = 0; i < 16; ++i) {
            const int q = qw + (i & 3) + 8 * (i >> 2) + 4 * u;
            const int col = h * 64 + dt * 32 + c;
            const float v = o[dt][i] * inv[i];
            const __bf16 hi = (__bf16)v;
            bf16x2 hv;
            hv[0] = hi;
            hv[1] = (__bf16)(v - (float)hi);
            *(bf16x2*)&ctx2[(((size_t)b * Sc + q) * Dc + col) * 2] = hv;
        }
}

extern "C" void kernel_launch(void* const* d_in, const int* in_sizes, int n_in,
                              void* d_out, int out_size, void* d_ws, size_t ws_size,
                              hipStream_t stream)
{
    const float* key   = (const float*)d_in[0];
    const float* value = (const float*)d_in[1];
    const float* query = (const float*)d_in[2];
    const int*   mask  = (const int*)  d_in[3];
    const float* Wq    = (const float*)d_in[4];
    const float* bq    = (const float*)d_in[5];
    const float* Wk    = (const float*)d_in[6];
    const float* bk    = (const float*)d_in[7];
    const float* Wv    = (const float*)d_in[8];
    const float* bv    = (const float*)d_in[9];
    const float* Wo    = (const float*)d_in[10];
    const float* bo    = (const float*)d_in[11];
    float* out = (float*)d_out;

    char* wsb = (char*)d_ws;
    __bf16* Qbf  = (__bf16*)(wsb);                                 // 8 MB
    __bf16* Kbf  = (__bf16*)(wsb + ((size_t)8  << 20));            // 8 MB
    __bf16* Vt   = (__bf16*)(wsb + ((size_t)16 << 20));            // 8 MB
    unsigned long long* mpk = (unsigned long long*)(wsb + ((size_t)24 << 20)); // 1 MB
    __bf16* Whi  = (__bf16*)(wsb + ((size_t)25 << 20));            // 6 MB (Wq,Wk,Wv)
    __bf16* Wo2  = (__bf16*)(wsb + ((size_t)31 << 20));            // 4 MB
    __bf16* ctx2 = (__bf16*)(wsb + ((size_t)35 << 20));            // 16 MB
    __bf16* Abf  = (__bf16*)(wsb + ((size_t)51 << 20));            // 24 MB

    dim3 gws(Dc * Dc / (256 * 4), 4);
    wsplit<<<gws, 256, 0, stream>>>(Wq, Wk, Wv, Wo, Whi, Wo2);

    dim3 gac(BSc * Dc / (256 * 8), 3);
    acast<<<gac, 256, 0, stream>>>(query, key, value, Abf);

    dim3 gqkv(BSc / 128, Dc / 128, 3);
    qkv_mfma<<<gqkv, 256, 0, stream>>>(Abf, Whi, bq, bk, bv, Qbf, Kbf, Vt);

    const int mask_n = Bc * Sc * Sc;
    mask_pack<<<mask_n / 1024, 256, 0, stream>>>(mask, mpk);

    dim3 gattn(Sc / 128, Bc * Hc);
    attn_mfma<<<gattn, 256, 0, stream>>>(Qbf, Kbf, Vt, mpk, ctx2);

    out_mfma<<<dim3(512), 256, 0, stream>>>(ctx2, Wo2, bo, out);
}

// Round 9
// 250.329 us; speedup vs baseline: 1.0709x; 1.0531x over previous
//
#include <hip/hip_runtime.h>
#include <math.h>

// MultiHeadedAttention  B=2, S=2048, D=1024, H=16, DH=64 (fp32 in/out)
// R19: revert to R13 configuration (best measured total, 251.1us) + XCD
// supertile rasters on qkv and out:
//  - attn: R12 core (dbuf 32KB, in-register softmax, permlane), epilogue
//    writes separate ctxHi/ctxLo (R13 — out prefers split streams).
//  - out: sweep64p triple-GLDS (W K=1024 + ctxHi + ctxLo), M64xN128,
//    1-D grid 512 with 8x8 supertile per XCD (R18-proven mapping).
//  - qkv: sweep128bb, 1-D 256 blocks/z, 4Mx8N supertile per XCD
//    (1MB A window + 2MB W fits 4MB L2).
// ws: Qbf@0 Kbf@8M Vt@16M mpk@32M Whi@33M ctxHi@41M ctxLo@49M Abf@57M

constexpr int Bc  = 2;
constexpr int Sc  = 2048;
constexpr int Dc  = 1024;
constexpr int Hc  = 16;
constexpr int DHc = 64;
constexpr int BSc = Bc * Sc;     // 4096

constexpr float LOG2E = 1.4426950408889634f;

typedef __bf16 bf16x8 __attribute__((ext_vector_type(8)));
typedef __bf16 bf16x4 __attribute__((ext_vector_type(4)));
typedef __bf16 bf16x2 __attribute__((ext_vector_type(2)));
typedef float  f32x4  __attribute__((ext_vector_type(4)));
typedef float  f32x16 __attribute__((ext_vector_type(16)));
typedef unsigned uint32x2 __attribute__((ext_vector_type(2)));
typedef unsigned uint32x4 __attribute__((ext_vector_type(4)));

#define GLDS16(gp, lp) __builtin_amdgcn_global_load_lds( \
    (const __attribute__((address_space(1))) void*)(gp), \
    (__attribute__((address_space(3))) void*)(lp), 16, 0, 0)

// ---------------------------------------------------------------------------
// Weight cast: Whi[z] = RNE bf16 of {Wq,Wk,Wv,Wo}
// ---------------------------------------------------------------------------
__global__ __launch_bounds__(256)
void wsplit(const float* __restrict__ W0, const float* __restrict__ W1,
            const float* __restrict__ W2, const float* __restrict__ W3,
            __bf16* __restrict__ out)
{
    const float* src[4] = {W0, W1, W2, W3};
    const int z = blockIdx.y;
    const size_t idx = ((size_t)blockIdx.x * 256 + threadIdx.x) * 4;
    const float4 v = *(const float4*)&src[z][idx];
    bf16x4 o;
    o[0] = (__bf16)v.x; o[1] = (__bf16)v.y; o[2] = (__bf16)v.z; o[3] = (__bf16)v.w;
    *(bf16x4*)&out[(size_t)z * Dc * Dc + idx] = o;
}

// ---------------------------------------------------------------------------
// Activation cast: Abf[z] = RNE bf16 of {query,key,value}, 8 elems/thread.
// ---------------------------------------------------------------------------
__global__ __launch_bounds__(256)
void acast(const float* __restrict__ A0, const float* __restrict__ A1,
           const float* __restrict__ A2, __bf16* __restrict__ out)
{
    const float* src[3] = {A0, A1, A2};
    const int z = blockIdx.y;
    const size_t idx = ((size_t)blockIdx.x * 256 + threadIdx.x) * 8;
    const float4 a = *(const float4*)&src[z][idx];
    const float4 b = *(const float4*)&src[z][idx + 4];
    bf16x8 o;
    o[0] = (__bf16)a.x; o[1] = (__bf16)a.y; o[2] = (__bf16)a.z; o[3] = (__bf16)a.w;
    o[4] = (__bf16)b.x; o[5] = (__bf16)b.y; o[6] = (__bf16)b.z; o[7] = (__bf16)b.w;
    *(bf16x8*)&out[(size_t)z * BSc * Dc + idx] = o;
}

// ---------------------------------------------------------------------------
// Pure double-GLDS K-sweep, M-tile 128 (qkv).
// ---------------------------------------------------------------------------
template<int KD>
__device__ __forceinline__ void sweep128bb(const __bf16* __restrict__ A,
                                           const __bf16* __restrict__ Wh,
                                           char* AsB, char* WsB,
                                           int gm0, int gn0, f32x4 acc[4][4])
{
    const int tid  = threadIdx.x;
    const int w    = tid >> 6;
    const int lane = tid & 63;
    const int cc   = lane & 15;
    const int g    = lane >> 4;
    const int wm   = (w & 1) * 64;
    const int wn   = (w >> 1) * 64;

    int wrow[4], wchk[4];
#pragma unroll
    for (int r = 0; r < 4; ++r) {
        const int L = r * 256 + tid;
        wrow[r] = L >> 3;
        wchk[r] = (L & 7) ^ (wrow[r] & 7);
    }

#pragma unroll
    for (int r = 0; r < 4; ++r) {
        GLDS16(Wh + (size_t)(gn0 + wrow[r]) * KD + wchk[r] * 8,
               WsB + (r * 256 + tid) * 16);
        GLDS16(A + (size_t)(gm0 + wrow[r]) * KD + wchk[r] * 8,
               AsB + (r * 256 + tid) * 16);
    }

    for (int it = 0; it < KD / 64; ++it) {
        const char* As = AsB + (it & 1) * 16384;
        const char* Ws = WsB + (it & 1) * 16384;
        __syncthreads();

        if (it + 1 < KD / 64) {
            const int kn = (it + 1) * 64;
            char* Wn = WsB + ((it + 1) & 1) * 16384;
            char* An = AsB + ((it + 1) & 1) * 16384;
#pragma unroll
            for (int r = 0; r < 4; ++r) {
                GLDS16(Wh + (size_t)(gn0 + wrow[r]) * KD + kn + wchk[r] * 8,
                       Wn + (r * 256 + tid) * 16);
                GLDS16(A + (size_t)(gm0 + wrow[r]) * KD + kn + wchk[r] * 8,
                       An + (r * 256 + tid) * 16);
            }
        }

        __builtin_amdgcn_s_setprio(1);
#pragma unroll
        for (int kk = 0; kk < 2; ++kk) {
            const int cb4 = (kk * 4 + g) << 4;
            bf16x8 af[4], bfr[4];
#pragma unroll
            for (int mt = 0; mt < 4; ++mt) {
                const int row = wm + mt * 16 + cc;
                af[mt] = *(const bf16x8*)(As + row * 128 + (cb4 ^ ((row & 7) << 4)));
            }
#pragma unroll
            for (int nt = 0; nt < 4; ++nt) {
                const int row = wn + nt * 16 + cc;
                bfr[nt] = *(const bf16x8*)(Ws + row * 128 + (cb4 ^ ((row & 7) << 4)));
            }
#pragma unroll
            for (int mt = 0; mt < 4; ++mt)
#pragma unroll
                for (int nt = 0; nt < 4; ++nt)
                    acc[mt][nt] = __builtin_amdgcn_mfma_f32_16x16x32_bf16(
                        af[mt], bfr[nt], acc[mt][nt], 0, 0, 0);
        }
        __builtin_amdgcn_s_setprio(0);
    }
}

// ---------------------------------------------------------------------------
// Pipelined hi/lo K-sweep, M64; all operands bf16 via global_load_lds dbuf.
// W dbuf 32K | Ahi dbuf 16K | Alo dbuf 16K.
// ---------------------------------------------------------------------------
__device__ __forceinline__ void sweep64p(const __bf16* __restrict__ Ahi,
                                         const __bf16* __restrict__ Alo,
                                         const __bf16* __restrict__ Wh,
                                         char* WsB, char* AhB, char* AlB,
                                         int gm0, int gn0, f32x4 acc[2][4])
{
    const int tid  = threadIdx.x;
    const int w    = tid >> 6;
    const int lane = tid & 63;
    const int cc   = lane & 15;
    const int g    = lane >> 4;
    const int wm   = (w & 1) * 32;
    const int wn   = (w >> 1) * 64;

    int wrow[4], wchk[4];
#pragma unroll
    for (int r = 0; r < 4; ++r) {
        const int L = r * 256 + tid;
        wrow[r] = L >> 3;
        wchk[r] = (L & 7) ^ (wrow[r] & 7);
    }
    int arow[2], achk[2];
#pragma unroll
    for (int r = 0; r < 2; ++r) {
        const int L = r * 256 + tid;
        arow[r] = L >> 3;
        achk[r] = (L & 7) ^ (arow[r] & 7);
    }

#pragma unroll
    for (int r = 0; r < 4; ++r)
        GLDS16(Wh + (size_t)(gn0 + wrow[r]) * Dc + wchk[r] * 8,
               WsB + (r * 256 + tid) * 16);
#pragma unroll
    for (int r = 0; r < 2; ++r) {
        GLDS16(Ahi + (size_t)(gm0 + arow[r]) * Dc + achk[r] * 8,
               AhB + (r * 256 + tid) * 16);
        GLDS16(Alo + (size_t)(gm0 + arow[r]) * Dc + achk[r] * 8,
               AlB + (r * 256 + tid) * 16);
    }

    for (int it = 0; it < Dc / 64; ++it) {
        const char* Ws = WsB + (it & 1) * 16384;
        const char* Ah = AhB + (it & 1) * 8192;
        const char* Al = AlB + (it & 1) * 8192;
        __syncthreads();

        if (it + 1 < Dc / 64) {
            const int kn = (it + 1) * 64;
            char* Wn = WsB + ((it + 1) & 1) * 16384;
            char* Hn = AhB + ((it + 1) & 1) * 8192;
            char* Ln = AlB + ((it + 1) & 1) * 8192;
#pragma unroll
            for (int r = 0; r < 4; ++r)
                GLDS16(Wh + (size_t)(gn0 + wrow[r]) * Dc + kn + wchk[r] * 8,
                       Wn + (r * 256 + tid) * 16);
#pragma unroll
            for (int r = 0; r < 2; ++r) {
                GLDS16(Ahi + (size_t)(gm0 + arow[r]) * Dc + kn + achk[r] * 8,
                       Hn + (r * 256 + tid) * 16);
                GLDS16(Alo + (size_t)(gm0 + arow[r]) * Dc + kn + achk[r] * 8,
                       Ln + (r * 256 + tid) * 16);
            }
        }

        __builtin_amdgcn_s_setprio(1);
#pragma unroll
        for (int kk = 0; kk < 2; ++kk) {
            const int cb4 = (kk * 4 + g) << 4;
            bf16x8 ahi[2], alo[2], bfr[4];
#pragma unroll
            for (int mt = 0; mt < 2; ++mt) {
                const int row = wm + mt * 16 + cc;
                const int off = row * 128 + (cb4 ^ ((row & 7) << 4));
                ahi[mt] = *(const bf16x8*)(Ah + off);
                alo[mt] = *(const bf16x8*)(Al + off);
            }
#pragma unroll
            for (int nt = 0; nt < 4; ++nt) {
                const int row = wn + nt * 16 + cc;
                bfr[nt] = *(const bf16x8*)(Ws + row * 128 + (cb4 ^ ((row & 7) << 4)));
            }
#pragma unroll
            for (int mt = 0; mt < 2; ++mt)
#pragma unroll
                for (int nt = 0; nt < 4; ++nt) {
                    acc[mt][nt] = __builtin_amdgcn_mfma_f32_16x16x32_bf16(
                        ahi[mt], bfr[nt], acc[mt][nt], 0, 0, 0);
                    acc[mt][nt] = __builtin_amdgcn_mfma_f32_16x16x32_bf16(
                        alo[mt], bfr[nt], acc[mt][nt], 0, 0, 0);
                }
        }
        __builtin_amdgcn_s_setprio(0);
    }
}

// ---------------------------------------------------------------------------
// QKV projection (double-GLDS). z==2 writes V^T [BH,DH,S] directly.
// 1-D 256 blocks/z, XCD-chunked 4Mx8N supertile raster.
// ---------------------------------------------------------------------------
__global__ __launch_bounds__(256)
void qkv_mfma(const __bf16* __restrict__ Abf, const __bf16* __restrict__ Whi,
              const float* __restrict__ bq, const float* __restrict__ bk,
              const float* __restrict__ bv,
              __bf16* __restrict__ Qo, __bf16* __restrict__ Ko, __bf16* __restrict__ Vt)
{
    __shared__ __align__(16) char smem[65536];   // A dbuf 32K | W dbuf 32K

    const int z = blockIdx.y;
    const float* bias = (z == 0) ? bq : (z == 1) ? bk : bv;
    const float scale = (z == 0) ? 0.125f * LOG2E : 1.0f;
    const __bf16* A   = Abf + (size_t)z * BSc * Dc;
    const __bf16* Wh  = Whi + (size_t)z * Dc * Dc;

    // XCD-chunked raster: lb = (bx%8)*32 + bx/8; XCD k = lb>>5 owns a
    // 4Mx8N supertile (A window 1MB + W 2MB -> L2-resident).
    const int lb  = (blockIdx.x & 7) * 32 + (blockIdx.x >> 3);
    const int idx = lb & 31;
    const int gm0 = ((lb >> 5) * 4 + (idx & 3)) * 128;
    const int gn0 = (idx >> 2) * 128;

    f32x4 acc[4][4];
#pragma unroll
    for (int mt = 0; mt < 4; ++mt)
#pragma unroll
        for (int nt = 0; nt < 4; ++nt) acc[mt][nt] = {0.f, 0.f, 0.f, 0.f};

    sweep128bb<Dc>(A, Wh, smem, smem + 32768, gm0, gn0, acc);

    const int tid = threadIdx.x;
    const int w = tid >> 6, lane = tid & 63;
    const int cc = lane & 15, g = lane >> 4;
    const int wm = (w & 1) * 64, wn = (w >> 1) * 64;

    float bias4[4];
#pragma unroll
    for (int nt = 0; nt < 4; ++nt) bias4[nt] = bias[gn0 + wn + nt * 16 + cc];

    if (z == 2) {
#pragma unroll
        for (int mt = 0; mt < 4; ++mt)
#pragma unroll
            for (int nt = 0; nt < 4; ++nt) {
                const int col = gn0 + wn + nt * 16 + cc;
                const int h = col >> 6, dh = col & 63;
                const int row0 = gm0 + wm + mt * 16 + g * 4;
                const int b = row0 >> 11, s0 = row0 & 2047;
                bf16x4 vv;
#pragma unroll
                for (int reg = 0; reg < 4; ++reg)
                    vv[reg] = (__bf16)(acc[mt][nt][reg] + bias4[nt]);
                *(bf16x4*)&Vt[(((size_t)(b * Hc + h)) * DHc + dh) * Sc + s0] = vv;
            }
    } else {
        __bf16* O = (z == 0) ? Qo : Ko;
#pragma unroll
        for (int mt = 0; mt < 4; ++mt)
#pragma unroll
            for (int nt = 0; nt < 4; ++nt) {
                const int col = gn0 + wn + nt * 16 + cc;
                const int h = col >> 6, dh = col & 63;
#pragma unroll
                for (int reg = 0; reg < 4; ++reg) {
                    const int row = gm0 + wm + mt * 16 + g * 4 + reg;
                    const int b = row >> 11, s = row & 2047;
                    O[(((size_t)(b * Hc + h)) * Sc + s) * DHc + dh] =
                        (__bf16)((acc[mt][nt][reg] + bias4[nt]) * scale);
                }
            }
    }
}

// ---------------------------------------------------------------------------
// Output projection: out = (ctxHi+ctxLo) @ Wo^T + bo, fp32 out.
// M64xN128 sweep64p; 1-D grid 512, XCD-chunked 8x8 supertile raster.
// ---------------------------------------------------------------------------
__global__ __launch_bounds__(256)
void out_mfma(const __bf16* __restrict__ ctxHi, const __bf16* __restrict__ ctxLo,
              const __bf16* __restrict__ Wohi,
              const float* __restrict__ bo, float* __restrict__ out)
{
    __shared__ __align__(16) char smem[65536];   // W dbuf 32K | Ahi 16K | Alo 16K

    const int lb = (blockIdx.x & 7) * 64 + (blockIdx.x >> 3);
    const int gm0 = ((lb >> 6) * 8 + (lb & 7)) * 64;
    const int gn0 = ((lb >> 3) & 7) * 128;

    f32x4 acc[2][4];
#pragma unroll
    for (int mt = 0; mt < 2; ++mt)
#pragma unroll
        for (int nt = 0; nt < 4; ++nt) acc[mt][nt] = {0.f, 0.f, 0.f, 0.f};

    sweep64p(ctxHi, ctxLo, Wohi, smem, smem + 32768, smem + 49152, gm0, gn0, acc);

    const int tid = threadIdx.x;
    const int w = tid >> 6, lane = tid & 63;
    const int cc = lane & 15, g = lane >> 4;
    const int wm = (w & 1) * 32, wn = (w >> 1) * 64;

    float bias4[4];
#pragma unroll
    for (int nt = 0; nt < 4; ++nt) bias4[nt] = bo[gn0 + wn + nt * 16 + cc];

#pragma unroll
    for (int mt = 0; mt < 2; ++mt)
#pragma unroll
        for (int nt = 0; nt < 4; ++nt) {
            const int col = gn0 + wn + nt * 16 + cc;
#pragma unroll
            for (int reg = 0; reg < 4; ++reg) {
                const int row = gm0 + wm + mt * 16 + g * 4 + reg;
                out[(size_t)row * Dc + col] = acc[mt][nt][reg] + bias4[nt];
            }
        }
}

// ---------------------------------------------------------------------------
// Bitpack mask: each wave packs 4 u64 words (256 elements).
// ---------------------------------------------------------------------------
__global__ __launch_bounds__(256)
void mask_pack(const int* __restrict__ mask, unsigned long long* __restrict__ out)
{
    const int lane = threadIdx.x & 63;
    const size_t waveBase = ((size_t)blockIdx.x * 4 + (threadIdx.x >> 6)) * 256;
    unsigned long long b0 = __ballot(mask[waveBase + lane]        != 0);
    unsigned long long b1 = __ballot(mask[waveBase + 64 + lane]   != 0);
    unsigned long long b2 = __ballot(mask[waveBase + 128 + lane]  != 0);
    unsigned long long b3 = __ballot(mask[waveBase + 192 + lane]  != 0);
    if (lane == 0) {
        unsigned long long* dst = out + (waveBase >> 6);
        dst[0] = b0; dst[1] = b1; dst[2] = b2; dst[3] = b3;
    }
}

// ---------------------------------------------------------------------------
// Flash attention (R12/R13 core): 32x32x16 MFMA, swapped QK^T, in-register
// softmax, permlane P redistribution. 4 waves x 32 q = 128 q/block,
// grid 16x32 = 512 blocks. K/V dbuf 32KB. Writes ctxHi/ctxLo.
// ---------------------------------------------------------------------------
__global__ __launch_bounds__(256, 2)
void attn_mfma(const __bf16* __restrict__ Q, const __bf16* __restrict__ K,
               const __bf16* __restrict__ Vt,
               const unsigned long long* __restrict__ mp,
               __bf16* __restrict__ ctxHi, __bf16* __restrict__ ctxLo)
{
    __shared__ __align__(16) char smem[32768];   // K/V dbuf: 2 x (8K K | 8K V)

    const int tid  = threadIdx.x;
    const int w    = tid >> 6;
    const int lane = tid & 63;
    const int c    = lane & 31;
    const int u    = lane >> 5;
    const int bh   = blockIdx.y;
    const int b    = bh >> 4;
    const int h    = bh & 15;
    const int qw   = blockIdx.x * 128 + w * 32;

    const __bf16* Qb  = Q  + (size_t)bh * Sc * DHc;
    const __bf16* Kb  = K  + (size_t)bh * Sc * DHc;
    const __bf16* Vtb = Vt + (size_t)bh * DHc * Sc;

    bf16x8 qa[4];
#pragma unroll
    for (int ch = 0; ch < 4; ++ch)
        qa[ch] = *(const bf16x8*)&Qb[(size_t)(qw + c) * DHc + ch * 16 + u * 8];

    f32x16 o[2];
#pragma unroll
    for (int dt = 0; dt < 2; ++dt)
#pragma unroll
        for (int i = 0; i < 16; ++i) o[dt][i] = 0.f;
    float lp[4] = {0.f, 0.f, 0.f, 0.f};

    const int ci[2] = {tid, 256 + tid};
    int rowi[2], ski[2];
#pragma unroll
    for (int i = 0; i < 2; ++i) {
        rowi[i] = ci[i] >> 3;
        ski[i]  = (ci[i] & 7) ^ (rowi[i] & 7);
    }

#pragma unroll
    for (int i = 0; i < 2; ++i) {
        GLDS16(Kb + (size_t)rowi[i] * DHc + ski[i] * 8,
               smem + ci[i] * 16);
        GLDS16(Vtb + (size_t)rowi[i] * Sc + ski[i] * 8,
               smem + 8192 + ci[i] * 16);
    }

    for (int it = 0; it < 32; ++it) {
        const char* Ks = smem + (it & 1) * 16384;
        const char* Vs = Ks + 8192;

        __syncthreads();

        if (it + 1 < 32) {
            char* Kn = smem + ((it + 1) & 1) * 16384;
            const int kn = (it + 1) * 64;
#pragma unroll
            for (int i = 0; i < 2; ++i) {
                GLDS16(Kb + (size_t)(kn + rowi[i]) * DHc + ski[i] * 8,
                       Kn + ci[i] * 16);
                GLDS16(Vtb + (size_t)rowi[i] * Sc + kn + ski[i] * 8,
                       Kn + 8192 + ci[i] * 16);
            }
        }

        const unsigned long long mw =
            mp[((size_t)(b * Sc + qw + c) << 5) + it];

        // ---- QK^T (swapped): P[k][q=c] in regs ----
        f32x16 sc[2];
        __builtin_amdgcn_s_setprio(1);
#pragma unroll
        for (int nt = 0; nt < 2; ++nt) {
            f32x16 z;
#pragma unroll
            for (int i = 0; i < 16; ++i) z[i] = -24.f;
#pragma unroll
            for (int ch = 0; ch < 4; ++ch) {
                const int row = nt * 32 + c;
                const bf16x8 kb = *(const bf16x8*)
                    (Ks + row * 128 + ((ch * 32 + u * 16) ^ ((row & 7) << 4)));
                z = __builtin_amdgcn_mfma_f32_32x32x16_bf16(kb, qa[ch], z, 0, 0, 0);
            }
            sc[nt] = z;
        }
        __builtin_amdgcn_s_setprio(0);

        // ---- softmax in-register ----
        unsigned pk[2][4][2];
#pragma unroll
        for (int nt = 0; nt < 2; ++nt)
#pragma unroll
            for (int rr = 0; rr < 4; ++rr) {
                const unsigned nib =
                    (unsigned)(mw >> (nt * 32 + rr * 8 + u * 4)) & 0xFu;
                float pv[4];
#pragma unroll
                for (int r = 0; r < 4; ++r) {
                    float p = __builtin_amdgcn_exp2f(sc[nt][rr * 4 + r]);
                    p = (nib & (1u << r)) ? 0.f : p;
                    lp[rr] += p;
                    pv[r] = p;
                }
                bf16x2 t0; t0[0] = (__bf16)pv[0]; t0[1] = (__bf16)pv[1];
                bf16x2 t1; t1[0] = (__bf16)pv[2]; t1[1] = (__bf16)pv[3];
                pk[nt][rr][0] = __builtin_bit_cast(unsigned, t0);
                pk[nt][rr][1] = __builtin_bit_cast(unsigned, t1);
            }

        // ---- redistribute to PV A-frags ----
        bf16x8 pa[4];
#pragma unroll
        for (int kc = 0; kc < 4; ++kc) {
            const int nt = kc >> 1;
            const int r0 = (kc & 1) * 2;
            uint32x2 s0 = __builtin_amdgcn_permlane32_swap(
                pk[nt][r0][0], pk[nt][r0 + 1][0], false, false);
            uint32x2 s1 = __builtin_amdgcn_permlane32_swap(
                pk[nt][r0][1], pk[nt][r0 + 1][1], false, false);
            uint32x4 wds;
            wds[0] = s0[0]; wds[1] = s1[0]; wds[2] = s0[1]; wds[3] = s1[1];
            pa[kc] = __builtin_bit_cast(bf16x8, wds);
        }

        // ---- PV ----
        __builtin_amdgcn_s_setprio(1);
#pragma unroll
        for (int dt = 0; dt < 2; ++dt)
#pragma unroll
            for (int kc = 0; kc < 4; ++kc) {
                const int row = dt * 32 + c;
                const bf16x8 vb = *(const bf16x8*)
                    (Vs + row * 128 + ((kc * 32 + u * 16) ^ ((row & 7) << 4)));
                o[dt] = __builtin_amdgcn_mfma_f32_32x32x16_bf16(pa[kc], vb, o[dt], 0, 0, 0);
            }
        __builtin_amdgcn_s_setprio(0);
    }

    // ---- epilogue ----
    float lsum = (lp[0] + lp[1]) + (lp[2] + lp[3]);
    lsum += __shfl_xor(lsum, 32);
    const float linv = 1.0f / lsum;

    float inv[16];
#pragma unroll
    for (int i = 0; i < 16; ++i)
        inv[i] = __shfl(linv, (i & 3) + 8 * (i >> 2) + 4 * u);

#pragma unroll
    for (int dt = 0; dt < 2; ++dt)
#pragma unroll
        for (int i = 0; i < 16; ++i) {
            const int q = qw + (i & 3) + 8 * (i >> 2) + 4 * u;
            const size_t idx = ((size_t)b * Sc + q) * Dc + h * 64 + dt * 32 + c;
            const float v = o[dt][i] * inv[i];
            const __bf16 hi = (__bf16)v;
            ctxHi[idx] = hi;
            ctxLo[idx] = (__bf16)(v - (float)hi);
        }
}

extern "C" void kernel_launch(void* const* d_in, const int* in_sizes, int n_in,
                              void* d_out, int out_size, void* d_ws, size_t ws_size,
                              hipStream_t stream)
{
    const float* key   = (const float*)d_in[0];
    const float* value = (const float*)d_in[1];
    const float* query = (const float*)d_in[2];
    const int*   mask  = (const int*)  d_in[3];
    const float* Wq    = (const float*)d_in[4];
    const float* bq    = (const float*)d_in[5];
    const float* Wk    = (const float*)d_in[6];
    const float* bk    = (const float*)d_in[7];
    const float* Wv    = (const float*)d_in[8];
    const float* bv    = (const float*)d_in[9];
    const float* Wo    = (const float*)d_in[10];
    const float* bo    = (const float*)d_in[11];
    float* out = (float*)d_out;

    char* wsb = (char*)d_ws;
    __bf16* Qbf  = (__bf16*)(wsb);                                 // 8 MB
    __bf16* Kbf  = (__bf16*)(wsb + ((size_t)8  << 20));            // 8 MB
    __bf16* Vt   = (__bf16*)(wsb + ((size_t)16 << 20));            // 8 MB
    unsigned long long* mpk = (unsigned long long*)(wsb + ((size_t)32 << 20)); // 1 MB
    __bf16* Whi  = (__bf16*)(wsb + ((size_t)33 << 20));            // 8 MB (Wq,Wk,Wv,Wo)
    __bf16* ctxHi = (__bf16*)(wsb + ((size_t)41 << 20));           // 8 MB
    __bf16* ctxLo = (__bf16*)(wsb + ((size_t)49 << 20));           // 8 MB
    __bf16* Abf  = (__bf16*)(wsb + ((size_t)57 << 20));            // 24 MB

    dim3 gws(Dc * Dc / (256 * 4), 4);
    wsplit<<<gws, 256, 0, stream>>>(Wq, Wk, Wv, Wo, Whi);

    dim3 gac(BSc * Dc / (256 * 8), 3);
    acast<<<gac, 256, 0, stream>>>(query, key, value, Abf);

    dim3 gqkv(256, 3);
    qkv_mfma<<<gqkv, 256, 0, stream>>>(Abf, Whi, bq, bk, bv, Qbf, Kbf, Vt);

    const int mask_n = Bc * Sc * Sc;
    mask_pack<<<mask_n / 1024, 256, 0, stream>>>(mask, mpk);

    dim3 gattn(Sc / 128, Bc * Hc);
    attn_mfma<<<gattn, 256, 0, stream>>>(Qbf, Kbf, Vt, mpk, ctxHi, ctxLo);

    out_mfma<<<dim3(512), 256, 0, stream>>>(ctxHi, ctxLo, Whi + (size_t)3 * Dc * Dc,
                                            bo, out);
}

// Round 10
// 247.940 us; speedup vs baseline: 1.0812x; 1.0096x over previous
//
#include <hip/hip_runtime.h>
#include <math.h>

// MultiHeadedAttention  B=2, S=2048, D=1024, H=16, DH=64 (fp32 in/out)
// R20 (baseline = R19, 250.3us):
//  - attn: 2 KV-tiles per barrier (64KB LDS, two 32KB halves; barriers
//    32->16, drain/skew amortized), zb=-24 persistent C-in register
//    (kills 32 v_mov/iter), both mask words hoisted per span.
//  - prep: wsplit+acast+mask_pack fused into one 18432-block kernel
//    (saves two launch ramps).
//  - qkv/out/sweeps unchanged from R19 (XCD supertile rasters).
// ws: Qbf@0 Kbf@8M Vt@16M mpk@32M Whi@33M ctxHi@41M ctxLo@49M Abf@57M

constexpr int Bc  = 2;
constexpr int Sc  = 2048;
constexpr int Dc  = 1024;
constexpr int Hc  = 16;
constexpr int DHc = 64;
constexpr int BSc = Bc * Sc;     // 4096

constexpr float LOG2E = 1.4426950408889634f;

typedef __bf16 bf16x8 __attribute__((ext_vector_type(8)));
typedef __bf16 bf16x4 __attribute__((ext_vector_type(4)));
typedef __bf16 bf16x2 __attribute__((ext_vector_type(2)));
typedef float  f32x4  __attribute__((ext_vector_type(4)));
typedef float  f32x16 __attribute__((ext_vector_type(16)));
typedef unsigned uint32x2 __attribute__((ext_vector_type(2)));
typedef unsigned uint32x4 __attribute__((ext_vector_type(4)));

#define GLDS16(gp, lp) __builtin_amdgcn_global_load_lds( \
    (const __attribute__((address_space(1))) void*)(gp), \
    (__attribute__((address_space(3))) void*)(lp), 16, 0, 0)

// ---------------------------------------------------------------------------
// prep: fused wsplit (blocks 0..4095) + acast (4096..10239) +
// mask_pack (10240..18431). No inter-part dependencies.
// ---------------------------------------------------------------------------
__global__ __launch_bounds__(256)
void prep(const float* __restrict__ W0, const float* __restrict__ W1,
          const float* __restrict__ W2, const float* __restrict__ W3,
          __bf16* __restrict__ Whi,
          const float* __restrict__ A0, const float* __restrict__ A1,
          const float* __restrict__ A2, __bf16* __restrict__ Abf,
          const int* __restrict__ mask, unsigned long long* __restrict__ mpk)
{
    const int bid = blockIdx.x;
    const int tid = threadIdx.x;

    if (bid < 4096) {
        // ---- wsplit: Whi[z] = bf16(Wz), z = bid>>10 ----
        const float* src[4] = {W0, W1, W2, W3};
        const int z  = bid >> 10;
        const int bx = bid & 1023;
        const size_t idx = ((size_t)bx * 256 + tid) * 4;
        const float4 v = *(const float4*)&src[z][idx];
        bf16x4 o;
        o[0] = (__bf16)v.x; o[1] = (__bf16)v.y;
        o[2] = (__bf16)v.z; o[3] = (__bf16)v.w;
        *(bf16x4*)&Whi[(size_t)z * Dc * Dc + idx] = o;
    } else if (bid < 10240) {
        // ---- acast: Abf[z] = bf16({query,key,value}) ----
        const float* src[3] = {A0, A1, A2};
        const int lin = bid - 4096;
        const int z  = lin >> 11;
        const int bx = lin & 2047;
        const size_t idx = ((size_t)bx * 256 + tid) * 8;
        const float4 a = *(const float4*)&src[z][idx];
        const float4 b = *(const float4*)&src[z][idx + 4];
        bf16x8 o;
        o[0] = (__bf16)a.x; o[1] = (__bf16)a.y; o[2] = (__bf16)a.z; o[3] = (__bf16)a.w;
        o[4] = (__bf16)b.x; o[5] = (__bf16)b.y; o[6] = (__bf16)b.z; o[7] = (__bf16)b.w;
        *(bf16x8*)&Abf[(size_t)z * BSc * Dc + idx] = o;
    } else {
        // ---- mask_pack: each wave packs 4 u64 words ----
        const int bx   = bid - 10240;
        const int lane = tid & 63;
        const size_t waveBase = ((size_t)bx * 4 + (tid >> 6)) * 256;
        unsigned long long b0 = __ballot(mask[waveBase + lane]        != 0);
        unsigned long long b1 = __ballot(mask[waveBase + 64 + lane]   != 0);
        unsigned long long b2 = __ballot(mask[waveBase + 128 + lane]  != 0);
        unsigned long long b3 = __ballot(mask[waveBase + 192 + lane]  != 0);
        if (lane == 0) {
            unsigned long long* dst = mpk + (waveBase >> 6);
            dst[0] = b0; dst[1] = b1; dst[2] = b2; dst[3] = b3;
        }
    }
}

// ---------------------------------------------------------------------------
// Pure double-GLDS K-sweep, M-tile 128 (qkv).
// ---------------------------------------------------------------------------
template<int KD>
__device__ __forceinline__ void sweep128bb(const __bf16* __restrict__ A,
                                           const __bf16* __restrict__ Wh,
                                           char* AsB, char* WsB,
                                           int gm0, int gn0, f32x4 acc[4][4])
{
    const int tid  = threadIdx.x;
    const int w    = tid >> 6;
    const int lane = tid & 63;
    const int cc   = lane & 15;
    const int g    = lane >> 4;
    const int wm   = (w & 1) * 64;
    const int wn   = (w >> 1) * 64;

    int wrow[4], wchk[4];
#pragma unroll
    for (int r = 0; r < 4; ++r) {
        const int L = r * 256 + tid;
        wrow[r] = L >> 3;
        wchk[r] = (L & 7) ^ (wrow[r] & 7);
    }

#pragma unroll
    for (int r = 0; r < 4; ++r) {
        GLDS16(Wh + (size_t)(gn0 + wrow[r]) * KD + wchk[r] * 8,
               WsB + (r * 256 + tid) * 16);
        GLDS16(A + (size_t)(gm0 + wrow[r]) * KD + wchk[r] * 8,
               AsB + (r * 256 + tid) * 16);
    }

    for (int it = 0; it < KD / 64; ++it) {
        const char* As = AsB + (it & 1) * 16384;
        const char* Ws = WsB + (it & 1) * 16384;
        __syncthreads();

        if (it + 1 < KD / 64) {
            const int kn = (it + 1) * 64;
            char* Wn = WsB + ((it + 1) & 1) * 16384;
            char* An = AsB + ((it + 1) & 1) * 16384;
#pragma unroll
            for (int r = 0; r < 4; ++r) {
                GLDS16(Wh + (size_t)(gn0 + wrow[r]) * KD + kn + wchk[r] * 8,
                       Wn + (r * 256 + tid) * 16);
                GLDS16(A + (size_t)(gm0 + wrow[r]) * KD + kn + wchk[r] * 8,
                       An + (r * 256 + tid) * 16);
            }
        }

        __builtin_amdgcn_s_setprio(1);
#pragma unroll
        for (int kk = 0; kk < 2; ++kk) {
            const int cb4 = (kk * 4 + g) << 4;
            bf16x8 af[4], bfr[4];
#pragma unroll
            for (int mt = 0; mt < 4; ++mt) {
                const int row = wm + mt * 16 + cc;
                af[mt] = *(const bf16x8*)(As + row * 128 + (cb4 ^ ((row & 7) << 4)));
            }
#pragma unroll
            for (int nt = 0; nt < 4; ++nt) {
                const int row = wn + nt * 16 + cc;
                bfr[nt] = *(const bf16x8*)(Ws + row * 128 + (cb4 ^ ((row & 7) << 4)));
            }
#pragma unroll
            for (int mt = 0; mt < 4; ++mt)
#pragma unroll
                for (int nt = 0; nt < 4; ++nt)
                    acc[mt][nt] = __builtin_amdgcn_mfma_f32_16x16x32_bf16(
                        af[mt], bfr[nt], acc[mt][nt], 0, 0, 0);
        }
        __builtin_amdgcn_s_setprio(0);
    }
}

// ---------------------------------------------------------------------------
// Pipelined hi/lo K-sweep, M64 (out projection).
// ---------------------------------------------------------------------------
__device__ __forceinline__ void sweep64p(const __bf16* __restrict__ Ahi,
                                         const __bf16* __restrict__ Alo,
                                         const __bf16* __restrict__ Wh,
                                         char* WsB, char* AhB, char* AlB,
                                         int gm0, int gn0, f32x4 acc[2][4])
{
    const int tid  = threadIdx.x;
    const int w    = tid >> 6;
    const int lane = tid & 63;
    const int cc   = lane & 15;
    const int g    = lane >> 4;
    const int wm   = (w & 1) * 32;
    const int wn   = (w >> 1) * 64;

    int wrow[4], wchk[4];
#pragma unroll
    for (int r = 0; r < 4; ++r) {
        const int L = r * 256 + tid;
        wrow[r] = L >> 3;
        wchk[r] = (L & 7) ^ (wrow[r] & 7);
    }
    int arow[2], achk[2];
#pragma unroll
    for (int r = 0; r < 2; ++r) {
        const int L = r * 256 + tid;
        arow[r] = L >> 3;
        achk[r] = (L & 7) ^ (arow[r] & 7);
    }

#pragma unroll
    for (int r = 0; r < 4; ++r)
        GLDS16(Wh + (size_t)(gn0 + wrow[r]) * Dc + wchk[r] * 8,
               WsB + (r * 256 + tid) * 16);
#pragma unroll
    for (int r = 0; r < 2; ++r) {
        GLDS16(Ahi + (size_t)(gm0 + arow[r]) * Dc + achk[r] * 8,
               AhB + (r * 256 + tid) * 16);
        GLDS16(Alo + (size_t)(gm0 + arow[r]) * Dc + achk[r] * 8,
               AlB + (r * 256 + tid) * 16);
    }

    for (int it = 0; it < Dc / 64; ++it) {
        const char* Ws = WsB + (it & 1) * 16384;
        const char* Ah = AhB + (it & 1) * 8192;
        const char* Al = AlB + (it & 1) * 8192;
        __syncthreads();

        if (it + 1 < Dc / 64) {
            const int kn = (it + 1) * 64;
            char* Wn = WsB + ((it + 1) & 1) * 16384;
            char* Hn = AhB + ((it + 1) & 1) * 8192;
            char* Ln = AlB + ((it + 1) & 1) * 8192;
#pragma unroll
            for (int r = 0; r < 4; ++r)
                GLDS16(Wh + (size_t)(gn0 + wrow[r]) * Dc + kn + wchk[r] * 8,
                       Wn + (r * 256 + tid) * 16);
#pragma unroll
            for (int r = 0; r < 2; ++r) {
                GLDS16(Ahi + (size_t)(gm0 + arow[r]) * Dc + kn + achk[r] * 8,
                       Hn + (r * 256 + tid) * 16);
                GLDS16(Alo + (size_t)(gm0 + arow[r]) * Dc + kn + achk[r] * 8,
                       Ln + (r * 256 + tid) * 16);
            }
        }

        __builtin_amdgcn_s_setprio(1);
#pragma unroll
        for (int kk = 0; kk < 2; ++kk) {
            const int cb4 = (kk * 4 + g) << 4;
            bf16x8 ahi[2], alo[2], bfr[4];
#pragma unroll
            for (int mt = 0; mt < 2; ++mt) {
                const int row = wm + mt * 16 + cc;
                const int off = row * 128 + (cb4 ^ ((row & 7) << 4));
                ahi[mt] = *(const bf16x8*)(Ah + off);
                alo[mt] = *(const bf16x8*)(Al + off);
            }
#pragma unroll
            for (int nt = 0; nt < 4; ++nt) {
                const int row = wn + nt * 16 + cc;
                bfr[nt] = *(const bf16x8*)(Ws + row * 128 + (cb4 ^ ((row & 7) << 4)));
            }
#pragma unroll
            for (int mt = 0; mt < 2; ++mt)
#pragma unroll
                for (int nt = 0; nt < 4; ++nt) {
                    acc[mt][nt] = __builtin_amdgcn_mfma_f32_16x16x32_bf16(
                        ahi[mt], bfr[nt], acc[mt][nt], 0, 0, 0);
                    acc[mt][nt] = __builtin_amdgcn_mfma_f32_16x16x32_bf16(
                        alo[mt], bfr[nt], acc[mt][nt], 0, 0, 0);
                }
        }
        __builtin_amdgcn_s_setprio(0);
    }
}

// ---------------------------------------------------------------------------
// QKV projection. 1-D 256 blocks/z, XCD-chunked 4Mx8N supertile raster.
// ---------------------------------------------------------------------------
__global__ __launch_bounds__(256)
void qkv_mfma(const __bf16* __restrict__ Abf, const __bf16* __restrict__ Whi,
              const float* __restrict__ bq, const float* __restrict__ bk,
              const float* __restrict__ bv,
              __bf16* __restrict__ Qo, __bf16* __restrict__ Ko, __bf16* __restrict__ Vt)
{
    __shared__ __align__(16) char smem[65536];   // A dbuf 32K | W dbuf 32K

    const int z = blockIdx.y;
    const float* bias = (z == 0) ? bq : (z == 1) ? bk : bv;
    const float scale = (z == 0) ? 0.125f * LOG2E : 1.0f;
    const __bf16* A   = Abf + (size_t)z * BSc * Dc;
    const __bf16* Wh  = Whi + (size_t)z * Dc * Dc;

    const int lb  = (blockIdx.x & 7) * 32 + (blockIdx.x >> 3);
    const int idx = lb & 31;
    const int gm0 = ((lb >> 5) * 4 + (idx & 3)) * 128;
    const int gn0 = (idx >> 2) * 128;

    f32x4 acc[4][4];
#pragma unroll
    for (int mt = 0; mt < 4; ++mt)
#pragma unroll
        for (int nt = 0; nt < 4; ++nt) acc[mt][nt] = {0.f, 0.f, 0.f, 0.f};

    sweep128bb<Dc>(A, Wh, smem, smem + 32768, gm0, gn0, acc);

    const int tid = threadIdx.x;
    const int w = tid >> 6, lane = tid & 63;
    const int cc = lane & 15, g = lane >> 4;
    const int wm = (w & 1) * 64, wn = (w >> 1) * 64;

    float bias4[4];
#pragma unroll
    for (int nt = 0; nt < 4; ++nt) bias4[nt] = bias[gn0 + wn + nt * 16 + cc];

    if (z == 2) {
#pragma unroll
        for (int mt = 0; mt < 4; ++mt)
#pragma unroll
            for (int nt = 0; nt < 4; ++nt) {
                const int col = gn0 + wn + nt * 16 + cc;
                const int h = col >> 6, dh = col & 63;
                const int row0 = gm0 + wm + mt * 16 + g * 4;
                const int b = row0 >> 11, s0 = row0 & 2047;
                bf16x4 vv;
#pragma unroll
                for (int reg = 0; reg < 4; ++reg)
                    vv[reg] = (__bf16)(acc[mt][nt][reg] + bias4[nt]);
                *(bf16x4*)&Vt[(((size_t)(b * Hc + h)) * DHc + dh) * Sc + s0] = vv;
            }
    } else {
        __bf16* O = (z == 0) ? Qo : Ko;
#pragma unroll
        for (int mt = 0; mt < 4; ++mt)
#pragma unroll
            for (int nt = 0; nt < 4; ++nt) {
                const int col = gn0 + wn + nt * 16 + cc;
                const int h = col >> 6, dh = col & 63;
#pragma unroll
                for (int reg = 0; reg < 4; ++reg) {
                    const int row = gm0 + wm + mt * 16 + g * 4 + reg;
                    const int b = row >> 11, s = row & 2047;
                    O[(((size_t)(b * Hc + h)) * Sc + s) * DHc + dh] =
                        (__bf16)((acc[mt][nt][reg] + bias4[nt]) * scale);
                }
            }
    }
}

// ---------------------------------------------------------------------------
// Output projection: out = (ctxHi+ctxLo) @ Wo^T + bo, fp32 out.
// M64xN128 sweep64p; 1-D grid 512, XCD-chunked 8x8 supertile raster.
// ---------------------------------------------------------------------------
__global__ __launch_bounds__(256)
void out_mfma(const __bf16* __restrict__ ctxHi, const __bf16* __restrict__ ctxLo,
              const __bf16* __restrict__ Wohi,
              const float* __restrict__ bo, float* __restrict__ out)
{
    __shared__ __align__(16) char smem[65536];   // W dbuf 32K | Ahi 16K | Alo 16K

    const int lb = (blockIdx.x & 7) * 64 + (blockIdx.x >> 3);
    const int gm0 = ((lb >> 6) * 8 + (lb & 7)) * 64;
    const int gn0 = ((lb >> 3) & 7) * 128;

    f32x4 acc[2][4];
#pragma unroll
    for (int mt = 0; mt < 2; ++mt)
#pragma unroll
        for (int nt = 0; nt < 4; ++nt) acc[mt][nt] = {0.f, 0.f, 0.f, 0.f};

    sweep64p(ctxHi, ctxLo, Wohi, smem, smem + 32768, smem + 49152, gm0, gn0, acc);

    const int tid = threadIdx.x;
    const int w = tid >> 6, lane = tid & 63;
    const int cc = lane & 15, g = lane >> 4;
    const int wm = (w & 1) * 32, wn = (w >> 1) * 64;

    float bias4[4];
#pragma unroll
    for (int nt = 0; nt < 4; ++nt) bias4[nt] = bo[gn0 + wn + nt * 16 + cc];

#pragma unroll
    for (int mt = 0; mt < 2; ++mt)
#pragma unroll
        for (int nt = 0; nt < 4; ++nt) {
            const int col = gn0 + wn + nt * 16 + cc;
#pragma unroll
            for (int reg = 0; reg < 4; ++reg) {
                const int row = gm0 + wm + mt * 16 + g * 4 + reg;
                out[(size_t)row * Dc + col] = acc[mt][nt][reg] + bias4[nt];
            }
        }
}

// ---------------------------------------------------------------------------
// attn helpers
// ---------------------------------------------------------------------------
__device__ __forceinline__ void stage_pair(const __bf16* Kb, const __bf16* Vtb,
                                           char* H, int t0,
                                           int rowi0, int ski0, int ci0,
                                           int rowi1, int ski1, int ci1)
{
    // tiles t0 (at H+0) and t0+1 (at H+16384); K@+0, V@+8192 within each
#pragma unroll
    for (int s = 0; s < 2; ++s) {
        char* B = H + s * 16384;
        const int kn = (t0 + s) * 64;
        GLDS16(Kb + (size_t)(kn + rowi0) * DHc + ski0 * 8, B + ci0 * 16);
        GLDS16(Vtb + (size_t)rowi0 * Sc + kn + ski0 * 8, B + 8192 + ci0 * 16);
        GLDS16(Kb + (size_t)(kn + rowi1) * DHc + ski1 * 8, B + ci1 * 16);
        GLDS16(Vtb + (size_t)rowi1 * Sc + kn + ski1 * 8, B + 8192 + ci1 * 16);
    }
}

__device__ __forceinline__ void tile_step(const char* Ks, const char* Vs,
                                          const bf16x8 qa[4], const f32x16& zb,
                                          unsigned long long mw, int c, int u,
                                          float lp[4], f32x16 o[2])
{
    // ---- QK^T (swapped), zb as first-MFMA C-in ----
    f32x16 sc[2];
    __builtin_amdgcn_s_setprio(1);
#pragma unroll
    for (int nt = 0; nt < 2; ++nt) {
        const int row = nt * 32 + c;
        const int rx  = (row & 7) << 4;
        const bf16x8 kb0 = *(const bf16x8*)(Ks + row * 128 + ((u * 16) ^ rx));
        f32x16 z = __builtin_amdgcn_mfma_f32_32x32x16_bf16(kb0, qa[0], zb, 0, 0, 0);
#pragma unroll
        for (int ch = 1; ch < 4; ++ch) {
            const bf16x8 kb = *(const bf16x8*)
                (Ks + row * 128 + ((ch * 32 + u * 16) ^ rx));
            z = __builtin_amdgcn_mfma_f32_32x32x16_bf16(kb, qa[ch], z, 0, 0, 0);
        }
        sc[nt] = z;
    }
    __builtin_amdgcn_s_setprio(0);

    // ---- softmax in-register ----
    unsigned pk[2][4][2];
#pragma unroll
    for (int nt = 0; nt < 2; ++nt)
#pragma unroll
        for (int rr = 0; rr < 4; ++rr) {
            const unsigned nib =
                (unsigned)(mw >> (nt * 32 + rr * 8 + u * 4)) & 0xFu;
            float pv[4];
#pragma unroll
            for (int r = 0; r < 4; ++r) {
                float p = __builtin_amdgcn_exp2f(sc[nt][rr * 4 + r]);
                p = (nib & (1u << r)) ? 0.f : p;
                lp[rr] += p;
                pv[r] = p;
            }
            bf16x2 t0; t0[0] = (__bf16)pv[0]; t0[1] = (__bf16)pv[1];
            bf16x2 t1; t1[0] = (__bf16)pv[2]; t1[1] = (__bf16)pv[3];
            pk[nt][rr][0] = __builtin_bit_cast(unsigned, t0);
            pk[nt][rr][1] = __builtin_bit_cast(unsigned, t1);
        }

    // ---- redistribute to PV A-frags ----
    bf16x8 pa[4];
#pragma unroll
    for (int kc = 0; kc < 4; ++kc) {
        const int nt = kc >> 1;
        const int r0 = (kc & 1) * 2;
        uint32x2 w0 = __builtin_amdgcn_permlane32_swap(
            pk[nt][r0][0], pk[nt][r0 + 1][0], false, false);
        uint32x2 w1 = __builtin_amdgcn_permlane32_swap(
            pk[nt][r0][1], pk[nt][r0 + 1][1], false, false);
        uint32x4 wds;
        wds[0] = w0[0]; wds[1] = w1[0]; wds[2] = w0[1]; wds[3] = w1[1];
        pa[kc] = __builtin_bit_cast(bf16x8, wds);
    }

    // ---- PV ----
    __builtin_amdgcn_s_setprio(1);
#pragma unroll
    for (int dt = 0; dt < 2; ++dt) {
        const int row = dt * 32 + c;
        const int rx  = (row & 7) << 4;
#pragma unroll
        for (int kc = 0; kc < 4; ++kc) {
            const bf16x8 vb = *(const bf16x8*)
                (Vs + row * 128 + ((kc * 32 + u * 16) ^ rx));
            o[dt] = __builtin_amdgcn_mfma_f32_32x32x16_bf16(pa[kc], vb, o[dt], 0, 0, 0);
        }
    }
    __builtin_amdgcn_s_setprio(0);
}

// ---------------------------------------------------------------------------
// Flash attention: 2 KV-tiles per barrier. 64KB LDS = two 32KB halves,
// each {tileA: K@0,V@8K | tileB: K@16K,V@24K}. Span j: barrier ->
// stage pair(2j+2,2j+3) into other half -> compute tiles 2j, 2j+1.
// 32x32x16 swapped QK^T, in-register softmax, permlane. 4 waves x 32 q.
// ---------------------------------------------------------------------------
__global__ __launch_bounds__(256, 2)
void attn_mfma(const __bf16* __restrict__ Q, const __bf16* __restrict__ K,
               const __bf16* __restrict__ Vt,
               const unsigned long long* __restrict__ mp,
               __bf16* __restrict__ ctxHi, __bf16* __restrict__ ctxLo)
{
    __shared__ __align__(16) char smem[65536];

    const int tid  = threadIdx.x;
    const int w    = tid >> 6;
    const int lane = tid & 63;
    const int c    = lane & 31;
    const int u    = lane >> 5;
    const int bh   = blockIdx.y;
    const int b    = bh >> 4;
    const int h    = bh & 15;
    const int qw   = blockIdx.x * 128 + w * 32;

    const __bf16* Qb  = Q  + (size_t)bh * Sc * DHc;
    const __bf16* Kb  = K  + (size_t)bh * Sc * DHc;
    const __bf16* Vtb = Vt + (size_t)bh * DHc * Sc;

    bf16x8 qa[4];
#pragma unroll
    for (int ch = 0; ch < 4; ++ch)
        qa[ch] = *(const bf16x8*)&Qb[(size_t)(qw + c) * DHc + ch * 16 + u * 8];

    f32x16 o[2], zb;
#pragma unroll
    for (int i = 0; i < 16; ++i) { o[0][i] = 0.f; o[1][i] = 0.f; zb[i] = -24.f; }
    float lp[4] = {0.f, 0.f, 0.f, 0.f};

    const int ci0 = tid,        ci1 = 256 + tid;
    const int rowi0 = ci0 >> 3, rowi1 = ci1 >> 3;
    const int ski0 = (ci0 & 7) ^ (rowi0 & 7);
    const int ski1 = (ci1 & 7) ^ (rowi1 & 7);

    const size_t mbase = ((size_t)(b * Sc + qw + c) << 5);

    // prologue: tiles 0,1 into half 0
    stage_pair(Kb, Vtb, smem, 0, rowi0, ski0, ci0, rowi1, ski1, ci1);

    for (int j = 0; j < 16; ++j) {
        __syncthreads();    // drains pair staged last span; all reads of the
                            // half being overwritten finished before this
        if (j + 1 < 16)
            stage_pair(Kb, Vtb, smem + ((j + 1) & 1) * 32768, 2 * j + 2,
                       rowi0, ski0, ci0, rowi1, ski1, ci1);

        const char* H = smem + (j & 1) * 32768;
        const unsigned long long mw0 = mp[mbase + 2 * j];
        const unsigned long long mw1 = mp[mbase + 2 * j + 1];

        tile_step(H,         H + 8192,  qa, zb, mw0, c, u, lp, o);
        tile_step(H + 16384, H + 24576, qa, zb, mw1, c, u, lp, o);
    }

    // ---- epilogue ----
    float lsum = (lp[0] + lp[1]) + (lp[2] + lp[3]);
    lsum += __shfl_xor(lsum, 32);
    const float linv = 1.0f / lsum;

    float inv[16];
#pragma unroll
    for (int i = 0; i < 16; ++i)
        inv[i] = __shfl(linv, (i & 3) + 8 * (i >> 2) + 4 * u);

#pragma unroll
    for (int dt = 0; dt < 2; ++dt)
#pragma unroll
        for (int i = 0; i < 16; ++i) {
            const int q = qw + (i & 3) + 8 * (i >> 2) + 4 * u;
            const size_t idx = ((size_t)b * Sc + q) * Dc + h * 64 + dt * 32 + c;
            const float v = o[dt][i] * inv[i];
            const __bf16 hi = (__bf16)v;
            ctxHi[idx] = hi;
            ctxLo[idx] = (__bf16)(v - (float)hi);
        }
}

extern "C" void kernel_launch(void* const* d_in, const int* in_sizes, int n_in,
                              void* d_out, int out_size, void* d_ws, size_t ws_size,
                              hipStream_t stream)
{
    const float* key   = (const float*)d_in[0];
    const float* value = (const float*)d_in[1];
    const float* query = (const float*)d_in[2];
    const int*   mask  = (const int*)  d_in[3];
    const float* Wq    = (const float*)d_in[4];
    const float* bq    = (const float*)d_in[5];
    const float* Wk    = (const float*)d_in[6];
    const float* bk    = (const float*)d_in[7];
    const float* Wv    = (const float*)d_in[8];
    const float* bv    = (const float*)d_in[9];
    const float* Wo    = (const float*)d_in[10];
    const float* bo    = (const float*)d_in[11];
    float* out = (float*)d_out;

    char* wsb = (char*)d_ws;
    __bf16* Qbf  = (__bf16*)(wsb);                                 // 8 MB
    __bf16* Kbf  = (__bf16*)(wsb + ((size_t)8  << 20));            // 8 MB
    __bf16* Vt   = (__bf16*)(wsb + ((size_t)16 << 20));            // 8 MB
    unsigned long long* mpk = (unsigned long long*)(wsb + ((size_t)32 << 20)); // 1 MB
    __bf16* Whi  = (__bf16*)(wsb + ((size_t)33 << 20));            // 8 MB (Wq,Wk,Wv,Wo)
    __bf16* ctxHi = (__bf16*)(wsb + ((size_t)41 << 20));           // 8 MB
    __bf16* ctxLo = (__bf16*)(wsb + ((size_t)49 << 20));           // 8 MB
    __bf16* Abf  = (__bf16*)(wsb + ((size_t)57 << 20));            // 24 MB

    prep<<<dim3(18432), 256, 0, stream>>>(Wq, Wk, Wv, Wo, Whi,
                                          query, key, value, Abf,
                                          mask, mpk);

    dim3 gqkv(256, 3);
    qkv_mfma<<<gqkv, 256, 0, stream>>>(Abf, Whi, bq, bk, bv, Qbf, Kbf, Vt);

    dim3 gattn(Sc / 128, Bc * Hc);
    attn_mfma<<<gattn, 256, 0, stream>>>(Qbf, Kbf, Vt, mpk, ctxHi, ctxLo);

    out_mfma<<<dim3(512), 256, 0, stream>>>(ctxHi, ctxLo, Whi + (size_t)3 * Dc * Dc,
                                            bo, out);
}